// Round 7
// baseline (703.838 us; speedup 1.0000x reference)
//
#include <hip/hip_runtime.h>

using u16 = unsigned short;
using u32 = unsigned int;
using bf16x8 = __attribute__((ext_vector_type(8))) short;
using f32x4  = __attribute__((ext_vector_type(4))) float;

__device__ __forceinline__ float bf2f(u16 v) { return __uint_as_float(((u32)v) << 16); }
__device__ __forceinline__ float blo(u32 u) { return __uint_as_float(u << 16); }
__device__ __forceinline__ float bhi(u32 u) { return __uint_as_float(u & 0xffff0000u); }
__device__ __forceinline__ u16 f2bf(float f) {
  u32 u = __float_as_uint(f);
  u += 0x7fffu + ((u >> 16) & 1u);   // RNE
  return (u16)(u >> 16);
}
__device__ __forceinline__ float fast_tanh(float x) {
  float cx = fminf(fmaxf(x, -9.f), 9.f);
  float e = __expf(2.f * cx);
  return (e - 1.f) / (e + 1.f);
}

// ---------------------------------------------------------------------------
// Weight prep: W (f32 [k][n]) -> WT (bf16 [n][k]) once, for W_a, W_b, Wk.
// WT is 32 KB -> L1-resident in proj/sem; no LDS staging needed there.
// ---------------------------------------------------------------------------
__global__ __launch_bounds__(256) void wprep_kernel(
    const float* __restrict__ Wa, const float* __restrict__ Wb,
    const float* __restrict__ Wk,
    u16* __restrict__ Ta, u16* __restrict__ Tb, u16* __restrict__ Tk)
{
  const int w = blockIdx.y;
  const float* W = (w == 0) ? Wa : (w == 1) ? Wb : Wk;
  u16* T = (w == 0) ? Ta : (w == 1) ? Tb : Tk;
  int idx = blockIdx.x * 256 + threadIdx.x;    // 0..16383
  int k = idx >> 7, n = idx & 127;
  T[n * 128 + k] = f2bf(W[idx]);
}

// ---------------------------------------------------------------------------
// K1: fused {proj (both types, WT via L1, NO LDS) | hist (4 rel)}.
// Interleave [proj,hist,hist] when gE==gproj so MFMA blocks co-reside with
// atomic-latency blocks. Zero LDS -> hist blocks get full occupancy.
// proj: D = WT-frag (A) x x-frag (B) = h^T tile; lane (col,g) holds feats
// c*16+4g+{0..3} of node nb+col; x split hi/lo bf16.
// ---------------------------------------------------------------------------
__global__ __launch_bounds__(256) void fused1_kernel(
    const float* __restrict__ x_a, const float* __restrict__ x_b,
    const u16* __restrict__ WTa, const u16* __restrict__ WTb,
    const float* __restrict__ b_a, const float* __restrict__ b_b,
    const float* __restrict__ at0a, const float* __restrict__ at1a,
    const float* __restrict__ at2a, const float* __restrict__ at3a,
    const float* __restrict__ at0b, const float* __restrict__ at1b,
    const float* __restrict__ at2b, const float* __restrict__ at3b,
    u16* __restrict__ ha, u16* __restrict__ hb,
    float* __restrict__ a0a, float* __restrict__ a1a,
    float* __restrict__ a2a, float* __restrict__ a3a,
    float* __restrict__ a0b, float* __restrict__ a1b,
    float* __restrict__ a2b, float* __restrict__ a3b,
    const int* __restrict__ e0, const int* __restrict__ e1,
    const int* __restrict__ e2, const int* __restrict__ e3,
    int* __restrict__ cnt,
    int N, int E, int gproj, int gE, int interleave)
{
  const int tid = threadIdx.x;
  const int bid = blockIdx.x;
  const int nP = 2 * gproj;

  int role, idx;
  if (interleave) {
    int slot = bid % 3, grp = bid / 3;
    if (slot == 0) { role = 0; idx = grp; }
    else           { role = 1; idx = grp * 2 + slot - 1; }
  } else {
    if (bid < nP) { role = 0; idx = bid; }
    else          { role = 1; idx = bid - nP; }
  }

  if (role == 1) {                 // ---- hist ----
    const int r = idx & 3, ex = idx >> 2;
    const int* ei = (r == 0) ? e0 : (r == 1) ? e1 : (r == 2) ? e2 : e3;
    int e = ex * 256 + tid;
    if (e < E) atomicAdd(&cnt[r * N + ei[E + e]], 1);
    return;
  }

  // ---- proj ----
  const int ty = idx >= gproj;
  const int bx = idx - (ty ? gproj : 0);
  const float* x    = ty ? x_b : x_a;
  const u16*  WT    = ty ? WTb : WTa;
  const float* bias = ty ? b_b : b_a;
  const float* att0 = ty ? at0b : at0a;
  const float* att1 = ty ? at1b : at1a;
  const float* att2 = ty ? at2b : at2a;
  const float* att3 = ty ? at3b : at3a;
  u16* h_out = ty ? hb : ha;
  float* al0 = ty ? a0b : a0a;
  float* al1 = ty ? a1b : a1a;
  float* al2 = ty ? a2b : a2a;
  float* al3 = ty ? a3b : a3a;

  const int lane = tid & 63, wl = tid >> 6;
  const int col = lane & 15, g = lane >> 4;
  const int nb = bx * 64 + wl * 16;
  const int node = nb + col;
  const bool ok = node < N;

  const int arow = min(node, N - 1);
  const float* xr = x + (size_t)arow * 128;
  bf16x8 xh[4], xlo[4];
#pragma unroll
  for (int t = 0; t < 4; ++t) {
    float4 u = *(const float4*)&xr[t * 32 + g * 8];
    float4 v = *(const float4*)&xr[t * 32 + g * 8 + 4];
    float e[8] = {u.x, u.y, u.z, u.w, v.x, v.y, v.z, v.w};
    bf16x8 h8, l8;
#pragma unroll
    for (int j = 0; j < 8; ++j) {
      u16 hbt = f2bf(e[j]);
      h8[j] = (short)hbt;
      l8[j] = (short)f2bf(e[j] - bf2f(hbt));
    }
    xh[t] = h8; xlo[t] = l8;
  }

  f32x4 acc[8];
#pragma unroll
  for (int c = 0; c < 8; ++c) {
    float4 bv = *(const float4*)&bias[c * 16 + g * 4];
    acc[c] = (f32x4){bv.x, bv.y, bv.z, bv.w};
  }

#pragma unroll
  for (int c = 0; c < 8; ++c) {
    const u16* wrow = WT + (c * 16 + col) * 128;   // L1-resident
#pragma unroll
    for (int t = 0; t < 4; ++t) {
      bf16x8 wf = *(const bf16x8*)&wrow[t * 32 + g * 8];
      acc[c] = __builtin_amdgcn_mfma_f32_16x16x32_bf16(wf, xh[t],  acc[c], 0, 0, 0);
      acc[c] = __builtin_amdgcn_mfma_f32_16x16x32_bf16(wf, xlo[t], acc[c], 0, 0, 0);
    }
  }

  if (ok) {
#pragma unroll
    for (int c = 0; c < 8; ++c) {
      uint2 hv;
      hv.x = (u32)f2bf(acc[c][0]) | ((u32)f2bf(acc[c][1]) << 16);
      hv.y = (u32)f2bf(acc[c][2]) | ((u32)f2bf(acc[c][3]) << 16);
      *(uint2*)(h_out + (size_t)node * 128 + c * 16 + g * 4) = hv;
    }
  }

#pragma unroll
  for (int c = 0; c < 8; ++c) {
    float4 a0v = *(const float4*)&att0[c * 16 + g * 4];
    float4 a1v = *(const float4*)&att1[c * 16 + g * 4];
    float4 a2v = *(const float4*)&att2[c * 16 + g * 4];
    float4 a3v = *(const float4*)&att3[c * 16 + g * 4];
    float p0 = acc[c][0] * a0v.x + acc[c][1] * a0v.y + acc[c][2] * a0v.z + acc[c][3] * a0v.w;
    float p1 = acc[c][0] * a1v.x + acc[c][1] * a1v.y + acc[c][2] * a1v.z + acc[c][3] * a1v.w;
    float p2 = acc[c][0] * a2v.x + acc[c][1] * a2v.y + acc[c][2] * a2v.z + acc[c][3] * a2v.w;
    float p3 = acc[c][0] * a3v.x + acc[c][1] * a3v.y + acc[c][2] * a3v.z + acc[c][3] * a3v.w;
    p0 += __shfl_xor(p0, 16); p0 += __shfl_xor(p0, 32);
    p1 += __shfl_xor(p1, 16); p1 += __shfl_xor(p1, 32);
    p2 += __shfl_xor(p2, 16); p2 += __shfl_xor(p2, 32);
    p3 += __shfl_xor(p3, 16); p3 += __shfl_xor(p3, 32);
    if (ok && g == 0) {
      al0[node * 8 + c] = p0;
      al1[node * 8 + c] = p1;
      al2[node * 8 + c] = p2;
      al3[node * 8 + c] = p3;
    }
  }
}

// ------------------------- CSR scans + scatter -----------------------------
__global__ __launch_bounds__(256) void scan1_kernel(int* __restrict__ data, int M,
                                                    int* __restrict__ bsum)
{
  __shared__ int ls[256];
  const int tid = threadIdx.x;
  const int base = blockIdx.x * 2048 + tid * 8;
  int v[8]; int s = 0;
#pragma unroll
  for (int j = 0; j < 8; ++j) v[j] = (base + j < M) ? data[base + j] : 0;
#pragma unroll
  for (int j = 0; j < 8; ++j) { int t = v[j]; v[j] = s; s += t; }
  ls[tid] = s;
  __syncthreads();
  for (int off = 1; off < 256; off <<= 1) {
    int t = (tid >= off) ? ls[tid - off] : 0;
    __syncthreads();
    ls[tid] += t;
    __syncthreads();
  }
  int texcl = ls[tid] - s;
#pragma unroll
  for (int j = 0; j < 8; ++j)
    if (base + j < M) data[base + j] = v[j] + texcl;
  if (tid == 255) bsum[blockIdx.x] = ls[255];
}

// scan3: block computes its own prefix over bsum (G1 <= 256), adds, mirrors.
__global__ __launch_bounds__(256) void scan3_kernel(int* __restrict__ data,
                                                    const int* __restrict__ bsum, int M,
                                                    int* __restrict__ cursor)
{
  __shared__ int rs[4];
  const int tid = threadIdx.x;
  int v = (tid < (int)blockIdx.x) ? bsum[tid] : 0;   // tid<bid<=G1-1 -> in range
#pragma unroll
  for (int off = 32; off > 0; off >>= 1) v += __shfl_down(v, off);
  if ((tid & 63) == 0) rs[tid >> 6] = v;
  __syncthreads();
  const int add = rs[0] + rs[1] + rs[2] + rs[3];
  const int base = blockIdx.x * 2048 + tid * 8;
#pragma unroll
  for (int j = 0; j < 8; ++j) {
    int i = base + j;
    if (i < M) { int t = data[i] + add; data[i] = t; cursor[i] = t; }
  }
}

__global__ __launch_bounds__(256) void scatter_kernel(
    const int* __restrict__ e0, const int* __restrict__ e1,
    const int* __restrict__ e2, const int* __restrict__ e3,
    int E, int N, int* __restrict__ cursor, int* __restrict__ ssrc)
{
  const int r = blockIdx.y;
  const int* ei = (r == 0) ? e0 : (r == 1) ? e1 : (r == 2) ? e2 : e3;
  int e = blockIdx.x * 256 + threadIdx.x;
  if (e >= E) return;
  int s = ei[e], d = ei[E + e];
  int p = atomicAdd(&cursor[r * N + d], 1);
  ssrc[p] = s;
}

// ---------------------------------------------------------------------------
// Fused segment-softmax + aggregate: 1 wave per dst node, 4-edge chunks.
// Output: relu(o) packed bf16.
// ---------------------------------------------------------------------------
__global__ __launch_bounds__(256) void aggregate_kernel(
    const int* __restrict__ off, const int* __restrict__ ssrc,
    const float* __restrict__ aS0, const float* __restrict__ aS1,
    const float* __restrict__ aS2, const float* __restrict__ aS3,
    const float* __restrict__ aD0, const float* __restrict__ aD1,
    const float* __restrict__ aD2, const float* __restrict__ aD3,
    const u16* __restrict__ h0, const u16* __restrict__ h1,
    const u16* __restrict__ h2, const u16* __restrict__ h3,
    u32* __restrict__ o0, u32* __restrict__ o1,
    u32* __restrict__ o2, u32* __restrict__ o3,
    int N, int E)
{
  const int r = blockIdx.y;
  const float* aS = (r == 0) ? aS0 : (r == 1) ? aS1 : (r == 2) ? aS2 : aS3;
  const float* aD = (r == 0) ? aD0 : (r == 1) ? aD1 : (r == 2) ? aD2 : aD3;
  const u16*   h  = (r == 0) ? h0  : (r == 1) ? h1  : (r == 2) ? h2  : h3;
  u32*         o  = (r == 0) ? o0  : (r == 1) ? o1  : (r == 2) ? o2  : o3;

  const int wave = threadIdx.x >> 6, lane = threadIdx.x & 63;
  const int n = blockIdx.x * 4 + wave;
  if (n >= N) return;
  const int head = lane >> 3;
  const int idx = r * N + n;
  const int p0 = off[idx];
  const int p1 = (idx + 1 < 4 * N) ? off[idx + 1] : 4 * E;
  const float aDv = aD[n * 8 + head];
  const u32* h32 = (const u32*)h;

  float acc0 = 0.f, acc1 = 0.f, den = 0.f;
  int p = p0;
  for (; p + 4 <= p1; p += 4) {
    const int s0 = ssrc[p], s1 = ssrc[p + 1], s2 = ssrc[p + 2], s3 = ssrc[p + 3];
    const float g0 = aS[s0 * 8 + head];
    const float g1 = aS[s1 * 8 + head];
    const float g2 = aS[s2 * 8 + head];
    const float g3 = aS[s3 * 8 + head];
    const u32 v0 = h32[s0 * 64 + lane];
    const u32 v1 = h32[s1 * 64 + lane];
    const u32 v2 = h32[s2 * 64 + lane];
    const u32 v3 = h32[s3 * 64 + lane];
    float l0 = g0 + aDv, l1 = g1 + aDv, l2 = g2 + aDv, l3 = g3 + aDv;
    l0 = fmaxf(l0, 0.2f * l0); l1 = fmaxf(l1, 0.2f * l1);
    l2 = fmaxf(l2, 0.2f * l2); l3 = fmaxf(l3, 0.2f * l3);
    const float w0 = __expf(l0), w1 = __expf(l1);
    const float w2 = __expf(l2), w3 = __expf(l3);
    den += (w0 + w1) + (w2 + w3);
    acc0 += w0 * blo(v0) + w1 * blo(v1) + w2 * blo(v2) + w3 * blo(v3);
    acc1 += w0 * bhi(v0) + w1 * bhi(v1) + w2 * bhi(v2) + w3 * bhi(v3);
  }
  const int rem = p1 - p;
  if (rem > 0) {
    const int s0 = ssrc[p];
    const int s1 = ssrc[(rem > 1) ? p + 1 : p];
    const int s2 = ssrc[(rem > 2) ? p + 2 : p];
    const float g0 = aS[s0 * 8 + head];
    const float g1 = aS[s1 * 8 + head];
    const float g2 = aS[s2 * 8 + head];
    const u32 v0 = h32[s0 * 64 + lane];
    const u32 v1 = h32[s1 * 64 + lane];
    const u32 v2 = h32[s2 * 64 + lane];
    float l0 = g0 + aDv, l1 = g1 + aDv, l2 = g2 + aDv;
    l0 = fmaxf(l0, 0.2f * l0); l1 = fmaxf(l1, 0.2f * l1); l2 = fmaxf(l2, 0.2f * l2);
    const float w0 = __expf(l0);
    const float w1 = (rem > 1) ? __expf(l1) : 0.f;
    const float w2 = (rem > 2) ? __expf(l2) : 0.f;
    den += w0 + w1 + w2;
    acc0 += w0 * blo(v0) + w1 * blo(v1) + w2 * blo(v2);
    acc1 += w0 * bhi(v0) + w1 * bhi(v1) + w2 * bhi(v2);
  }
  const float inv = 1.f / (den + 1e-16f);
  const float r0 = fmaxf(acc0 * inv, 0.f);
  const float r1 = fmaxf(acc1 * inv, 0.f);
  o[n * 64 + lane] = (u32)f2bf(r0) | ((u32)f2bf(r1) << 16);
}

// ---------------------------------------------------------------------------
// K2: fused {bn 5-moment stats (attn-independent) | MFMA semantic score}.
// sem reads WkT via L1 (no LDS staging); tiny LDS scratch for stats only.
// ---------------------------------------------------------------------------
__global__ __launch_bounds__(256) void fused2_kernel(
    const u32* __restrict__ oba, const u32* __restrict__ oaa,
    const u32* __restrict__ oab, const u32* __restrict__ obb,
    const u16* __restrict__ WkT, const float* __restrict__ bk,
    const float* __restrict__ q, float* __restrict__ scores,
    float* __restrict__ sums_a, float* __restrict__ sums_b,
    int N, int R, int gproj)
{
  __shared__ float sm[640];
  __shared__ float red[4];
  const int tid = threadIdx.x;
  const int bid = blockIdx.x;

  if (bid < 512) {                       // ---- bn 5-moment stats ----
    const int t = bid >> 8, bx = bid & 255;
    const u32* p0 = t ? oab : oba;
    const u32* p1 = t ? obb : oaa;
    float* sums = t ? sums_b : sums_a;
    const int tc = tid & 31, tr = tid >> 5;
    float s0[4] = {0,0,0,0}, s1[4] = {0,0,0,0};
    float q00[4] = {0,0,0,0}, q11[4] = {0,0,0,0}, q01[4] = {0,0,0,0};
    const int rend = min((bx + 1) * R, N);
    for (int row = bx * R + tr; row < rend; row += 8) {
      uint2 v0 = *(const uint2*)&p0[row * 64 + tc * 2];
      uint2 v1 = *(const uint2*)&p1[row * 64 + tc * 2];
      float r0[4] = {blo(v0.x), bhi(v0.x), blo(v0.y), bhi(v0.y)};
      float r1[4] = {blo(v1.x), bhi(v1.x), blo(v1.y), bhi(v1.y)};
#pragma unroll
      for (int j = 0; j < 4; ++j) {
        s0[j] += r0[j]; s1[j] += r1[j];
        q00[j] += r0[j] * r0[j]; q11[j] += r1[j] * r1[j];
        q01[j] += r0[j] * r1[j];
      }
    }
    for (int i = tid; i < 640; i += 256) sm[i] = 0.f;
    __syncthreads();
#pragma unroll
    for (int j = 0; j < 4; ++j) {
      int f = tc * 4 + j;
      atomicAdd(&sm[f], s0[j]);
      atomicAdd(&sm[128 + f], s1[j]);
      atomicAdd(&sm[256 + f], q00[j]);
      atomicAdd(&sm[384 + f], q11[j]);
      atomicAdd(&sm[512 + f], q01[j]);
    }
    __syncthreads();
    for (int i = tid; i < 640; i += 256) atomicAdd(&sums[i], sm[i]);
    return;
  }

  // ---- sem_score ----
  const int sid = bid - 512;
  const int rel = sid & 3, bx = sid >> 2;
  const u32* op = (rel == 0) ? oba : (rel == 1) ? oaa : (rel == 2) ? oab : obb;
  const u16* o = (const u16*)op;

  const int lane = tid & 63, wl = tid >> 6;
  const int col = lane & 15, g = lane >> 4;
  const int nb = bx * 64 + wl * 16;

  float bv[8], qv[8];
#pragma unroll
  for (int c = 0; c < 8; ++c) {
    bv[c] = bk[c * 16 + col];
    qv[c] = q[c * 16 + col];
  }

  const int arow = min(nb + col, N - 1);
  const u16* orow = o + (size_t)arow * 128;
  bf16x8 af[4];
#pragma unroll
  for (int t = 0; t < 4; ++t) af[t] = *(const bf16x8*)&orow[t * 32 + g * 8];

  f32x4 acc[8];
#pragma unroll
  for (int c = 0; c < 8; ++c) acc[c] = (f32x4){bv[c], bv[c], bv[c], bv[c]};

#pragma unroll
  for (int c = 0; c < 8; ++c) {
    const u16* wrow = WkT + (c * 16 + col) * 128;   // L1-resident
#pragma unroll
    for (int t = 0; t < 4; ++t) {
      bf16x8 bf = *(const bf16x8*)&wrow[t * 32 + g * 8];
      acc[c] = __builtin_amdgcn_mfma_f32_16x16x32_bf16(af[t], bf, acc[c], 0, 0, 0);
    }
  }

  float p = 0.f;
  const int rowbase = nb + g * 4;
#pragma unroll
  for (int c = 0; c < 8; ++c) {
#pragma unroll
    for (int i = 0; i < 4; ++i) {
      int node = rowbase + i;
      if (node < N) p += fast_tanh(acc[c][i]) * qv[c];
    }
  }
#pragma unroll
  for (int off = 32; off > 0; off >>= 1) p += __shfl_down(p, off);
  if (lane == 0) red[wl] = p;
  __syncthreads();
  if (tid == 0) atomicAdd(&scores[rel], red[0] + red[1] + red[2] + red[3]);
}

// ---------------------------------------------------------------------------
// bn_final: inline semantic softmax + moment combine + normalize + write.
// ---------------------------------------------------------------------------
__global__ __launch_bounds__(256) void bn_final_kernel(
    const u32* __restrict__ oba, const u32* __restrict__ oaa,
    const u32* __restrict__ oab, const u32* __restrict__ obb,
    const float* __restrict__ scores, const float* __restrict__ sums_a,
    const float* __restrict__ sums_b,
    const float* __restrict__ gamma, const float* __restrict__ beta,
    float* __restrict__ out, int N)
{
  const int t = blockIdx.y;
  const u32* o0 = t ? oab : oba;
  const u32* o1 = t ? obb : oaa;
  const float* sums = t ? sums_b : sums_a;
  float* op = out + (size_t)t * N * 128;

  const float invN = 1.f / (float)N;
  const float sc0 = scores[2 * t] * invN, sc1 = scores[2 * t + 1] * invN;
  const float m = fmaxf(sc0, sc1);
  const float e0 = expf(sc0 - m), e1 = expf(sc1 - m);
  const float einv = 1.f / (e0 + e1);
  const float a0 = e0 * einv, a1 = e1 * einv;

  __shared__ float scale[128], shift[128];
  if (threadIdx.x < 128) {
    int f = threadIdx.x;
    float S0 = sums[f], S1 = sums[128 + f];
    float Q00 = sums[256 + f], Q11 = sums[384 + f], Q01 = sums[512 + f];
    float mu = (a0 * S0 + a1 * S1) * invN;
    float msq = (a0 * a0 * Q00 + 2.f * a0 * a1 * Q01 + a1 * a1 * Q11) * invN;
    float var = fmaxf(msq - mu * mu, 0.f);
    float rs = rsqrtf(var + 1e-5f);
    float gm = gamma[f] * rs;
    scale[f] = gm;
    shift[f] = beta[f] - mu * gm;
  }
  __syncthreads();
  size_t total = (size_t)N * 128;
  for (size_t base = ((size_t)blockIdx.x * 256 + threadIdx.x) * 8; base < total;
       base += (size_t)gridDim.x * 2048) {
    int f0 = (int)(base & 127);
    uint4 p = *(const uint4*)&o0[base >> 1];
    uint4 q = *(const uint4*)&o1[base >> 1];
    float4 r0, r1;
    r0.x = (a0 * blo(p.x) + a1 * blo(q.x)) * scale[f0 + 0] + shift[f0 + 0];
    r0.y = (a0 * bhi(p.x) + a1 * bhi(q.x)) * scale[f0 + 1] + shift[f0 + 1];
    r0.z = (a0 * blo(p.y) + a1 * blo(q.y)) * scale[f0 + 2] + shift[f0 + 2];
    r0.w = (a0 * bhi(p.y) + a1 * bhi(q.y)) * scale[f0 + 3] + shift[f0 + 3];
    r1.x = (a0 * blo(p.z) + a1 * blo(q.z)) * scale[f0 + 4] + shift[f0 + 4];
    r1.y = (a0 * bhi(p.z) + a1 * bhi(q.z)) * scale[f0 + 5] + shift[f0 + 5];
    r1.z = (a0 * blo(p.w) + a1 * blo(q.w)) * scale[f0 + 6] + shift[f0 + 6];
    r1.w = (a0 * bhi(p.w) + a1 * bhi(q.w)) * scale[f0 + 7] + shift[f0 + 7];
    *(float4*)&op[base] = r0;
    *(float4*)&op[base + 4] = r1;
  }
}

extern "C" void kernel_launch(void* const* d_in, const int* in_sizes, int n_in,
                              void* d_out, int out_size, void* d_ws, size_t ws_size,
                              hipStream_t stream)
{
  const float* x_a      = (const float*)d_in[0];
  const float* x_b      = (const float*)d_in[1];
  const int* ei_ab      = (const int*)d_in[2];
  const int* ei_ba      = (const int*)d_in[3];
  const int* ei_aa      = (const int*)d_in[4];
  const int* ei_bb      = (const int*)d_in[5];
  const float* W_a      = (const float*)d_in[6];
  const float* b_a      = (const float*)d_in[7];
  const float* W_b      = (const float*)d_in[8];
  const float* b_b      = (const float*)d_in[9];
  const float* att_ab_s = (const float*)d_in[10];
  const float* att_ab_d = (const float*)d_in[11];
  const float* att_ba_s = (const float*)d_in[12];
  const float* att_ba_d = (const float*)d_in[13];
  const float* att_aa_s = (const float*)d_in[14];
  const float* att_aa_d = (const float*)d_in[15];
  const float* att_bb_s = (const float*)d_in[16];
  const float* att_bb_d = (const float*)d_in[17];
  const float* Wk       = (const float*)d_in[18];
  const float* bk       = (const float*)d_in[19];
  const float* q        = (const float*)d_in[20];
  const float* gamma    = (const float*)d_in[21];
  const float* beta     = (const float*)d_in[22];

  const int N = in_sizes[0] / 128;
  const int E = in_sizes[2] / 2;

  char* wp = (char*)d_ws;
  auto alloc = [&](size_t bytes) -> void* {
    void* p = (void*)wp;
    wp += (bytes + 255) & ~(size_t)255;
    return p;
  };
  u16* h_a = (u16*)alloc((size_t)N * 128 * 2);
  u16* h_b = (u16*)alloc((size_t)N * 128 * 2);
  float* A[8];
  for (int i = 0; i < 8; ++i) A[i] = (float*)alloc((size_t)N * 8 * 4);
  int* off    = (int*)alloc((size_t)4 * N * 4);
  int* cursor = (int*)alloc((size_t)4 * N * 4);
  int* bsum   = (int*)alloc(1024);
  int* ssrc   = (int*)alloc((size_t)4 * E * 4);
  u32* o_ab = (u32*)alloc((size_t)N * 64 * 4);   // packed relu bf16
  u32* o_ba = (u32*)alloc((size_t)N * 64 * 4);
  u32* o_aa = (u32*)alloc((size_t)N * 64 * 4);
  u32* o_bb = (u32*)alloc((size_t)N * 64 * 4);
  float* scores = (float*)alloc(16);             // 256B slot
  float* sums_a = (float*)alloc(2560);           // 5 x 128 f32
  float* sums_b = (float*)alloc(2560);
  u16* WT_a = (u16*)alloc(128 * 128 * 2);
  u16* WT_b = (u16*)alloc(128 * 128 * 2);
  u16* WT_k = (u16*)alloc(128 * 128 * 2);
  if ((size_t)(wp - (char*)d_ws) > ws_size) return;

  hipMemsetAsync(off, 0, (size_t)4 * N * 4, stream);
  hipMemsetAsync(scores, 0, 5376, stream);       // scores+sums_a+sums_b contiguous

  // --- weight prep (W_a, W_b, Wk -> transposed bf16; 32 KB each, L1-fit) ---
  dim3 gw(64, 3);
  wprep_kernel<<<gw, 256, 0, stream>>>(W_a, W_b, Wk, WT_a, WT_b, WT_k);

  // --- K1: proj (both types) | hist (4 rel) ---
  // relation order: 0=ab 1=ba 2=aa 3=bb
  // type a att slots: ab_s, aa_s, aa_d, ba_d -> A[0..3]
  // type b att slots: ab_d, bb_s, bb_d, ba_s -> A[4..7]
  const int gproj = (N + 63) / 64;
  const int gE = (E + 255) / 256;
  const int interleave = (gE == gproj) ? 1 : 0;
  const int g1total = 2 * gproj + 4 * gE;
  fused1_kernel<<<g1total, 256, 0, stream>>>(
      x_a, x_b, WT_a, WT_b, b_a, b_b,
      att_ab_s, att_aa_s, att_aa_d, att_ba_d,
      att_ab_d, att_bb_s, att_bb_d, att_ba_s,
      h_a, h_b,
      A[0], A[1], A[2], A[3], A[4], A[5], A[6], A[7],
      ei_ab, ei_ba, ei_aa, ei_bb,
      off, N, E, gproj, gE, interleave);

  // --- CSR scans + scatter (scan2 folded into scan3) ---
  const int M = 4 * N;
  const int G1 = (M + 2047) / 2048;          // <= 256 for N <= 131072
  scan1_kernel<<<G1, 256, 0, stream>>>(off, M, bsum);
  scan3_kernel<<<G1, 256, 0, stream>>>(off, bsum, M, cursor);
  dim3 gsc(gE, 4);
  scatter_kernel<<<gsc, 256, 0, stream>>>(ei_ab, ei_ba, ei_aa, ei_bb, E, N, cursor, ssrc);

  // --- fused softmax + aggregate ---
  dim3 gag((N + 3) / 4, 4);
  aggregate_kernel<<<gag, 256, 0, stream>>>(
      off, ssrc,
      A[0], A[7], A[1], A[5],          // aS per relation: ab,ba,aa,bb
      A[4], A[3], A[2], A[6],          // aD per relation
      h_a, h_b, h_a, h_b,
      o_ab, o_ba, o_aa, o_bb, N, E);

  // --- K2: bn 5-moment stats | semantic scores (slot order ba,aa,ab,bb) ---
  const int R = (N + 255) / 256;
  const int g2total = 512 + 4 * gproj;
  fused2_kernel<<<g2total, 256, 0, stream>>>(
      o_ba, o_aa, o_ab, o_bb, WT_k, bk, q, scores, sums_a, sums_b, N, R, gproj);

  // --- bn_final with inline softmax + moment combine ---
  float* out = (float*)d_out;
  dim3 gbf(1024, 2);
  bn_final_kernel<<<gbf, 256, 0, stream>>>(o_ba, o_aa, o_ab, o_bb, scores,
                                           sums_a, sums_b, gamma, beta, out, N);
}

// Round 8
// 636.947 us; speedup vs baseline: 1.1050x; 1.1050x over previous
//
#include <hip/hip_runtime.h>

using u16 = unsigned short;
using u32 = unsigned int;
using bf16x8 = __attribute__((ext_vector_type(8))) short;
using f32x4  = __attribute__((ext_vector_type(4))) float;

__device__ __forceinline__ float bf2f(u16 v) { return __uint_as_float(((u32)v) << 16); }
__device__ __forceinline__ float blo(u32 u) { return __uint_as_float(u << 16); }
__device__ __forceinline__ float bhi(u32 u) { return __uint_as_float(u & 0xffff0000u); }
__device__ __forceinline__ u16 f2bf(float f) {
  u32 u = __float_as_uint(f);
  u += 0x7fffu + ((u >> 16) & 1u);   // RNE
  return (u16)(u >> 16);
}
__device__ __forceinline__ float fast_tanh(float x) {
  float cx = fminf(fmaxf(x, -9.f), 9.f);
  float e = __expf(2.f * cx);
  return (e - 1.f) / (e + 1.f);
}

// ---------------------------------------------------------------------------
// Weight prep: W (f32 [k][n]) -> WT (bf16 [n][k]) once, for W_a, W_b, Wk.
// Downstream kernels stage WT into LDS with plain uint4 copies (no f2bf,
// conflict-free) — LDS keeps W-frag reads off the L2 latency path.
// ---------------------------------------------------------------------------
__global__ __launch_bounds__(256) void wprep_kernel(
    const float* __restrict__ Wa, const float* __restrict__ Wb,
    const float* __restrict__ Wk,
    u16* __restrict__ Ta, u16* __restrict__ Tb, u16* __restrict__ Tk)
{
  const int w = blockIdx.y;
  const float* W = (w == 0) ? Wa : (w == 1) ? Wb : Wk;
  u16* T = (w == 0) ? Ta : (w == 1) ? Tb : Tk;
  int idx = blockIdx.x * 256 + threadIdx.x;    // 0..16383
  int k = idx >> 7, n = idx & 127;
  T[n * 128 + k] = f2bf(W[idx]);
}

// ---------------------------------------------------------------------------
// K1: fused {proj (both types, WT uint4-staged in LDS) | hist (4 rel)}.
// Interleave [proj,hist,hist] (gE==gproj when E==4N) so MFMA blocks co-reside
// with atomic-latency hist blocks on each CU.
// proj: D = WT-frag (A) x x-frag (B) = h^T tile; lane (col,g) holds feats
// c*16+4g+{0..3} of node nb+col; x split hi/lo bf16.
// ---------------------------------------------------------------------------
__global__ __launch_bounds__(256) void fused1_kernel(
    const float* __restrict__ x_a, const float* __restrict__ x_b,
    const u16* __restrict__ WTa, const u16* __restrict__ WTb,
    const float* __restrict__ b_a, const float* __restrict__ b_b,
    const float* __restrict__ at0a, const float* __restrict__ at1a,
    const float* __restrict__ at2a, const float* __restrict__ at3a,
    const float* __restrict__ at0b, const float* __restrict__ at1b,
    const float* __restrict__ at2b, const float* __restrict__ at3b,
    u16* __restrict__ ha, u16* __restrict__ hb,
    float* __restrict__ a0a, float* __restrict__ a1a,
    float* __restrict__ a2a, float* __restrict__ a3a,
    float* __restrict__ a0b, float* __restrict__ a1b,
    float* __restrict__ a2b, float* __restrict__ a3b,
    const int* __restrict__ e0, const int* __restrict__ e1,
    const int* __restrict__ e2, const int* __restrict__ e3,
    int* __restrict__ cnt,
    int N, int E, int gproj, int gE, int interleave)
{
  __shared__ __align__(16) u16 WTl[128 * 136];
  const int tid = threadIdx.x;
  const int bid = blockIdx.x;
  const int nP = 2 * gproj;

  int role, idx;
  if (interleave) {
    int slot = bid % 3, grp = bid / 3;
    if (slot == 0) { role = 0; idx = grp; }
    else           { role = 1; idx = grp * 2 + slot - 1; }
  } else {
    if (bid < nP) { role = 0; idx = bid; }
    else          { role = 1; idx = bid - nP; }
  }

  if (role == 1) {                 // ---- hist ----
    const int r = idx & 3, ex = idx >> 2;
    const int* ei = (r == 0) ? e0 : (r == 1) ? e1 : (r == 2) ? e2 : e3;
    int e = ex * 256 + tid;
    if (e < E) atomicAdd(&cnt[r * N + ei[E + e]], 1);
    return;
  }

  // ---- proj ----
  const int ty = idx >= gproj;
  const int bx = idx - (ty ? gproj : 0);
  const float* x    = ty ? x_b : x_a;
  const u16*  WT    = ty ? WTb : WTa;
  const float* bias = ty ? b_b : b_a;
  const float* att0 = ty ? at0b : at0a;
  const float* att1 = ty ? at1b : at1a;
  const float* att2 = ty ? at2b : at2a;
  const float* att3 = ty ? at3b : at3a;
  u16* h_out = ty ? hb : ha;
  float* al0 = ty ? a0b : a0a;
  float* al1 = ty ? a1b : a1a;
  float* al2 = ty ? a2b : a2a;
  float* al3 = ty ? a3b : a3a;

  // stage WT -> LDS with aligned uint4 copies (no conversion, conflict-free)
  const uint4* Wg = (const uint4*)WT;          // 2048 x 16B
#pragma unroll
  for (int i = 0; i < 8; ++i) {
    int id = tid + 256 * i;                    // n = id>>4, k8 = (id&15)*8
    uint4 v = Wg[id];
    int n = id >> 4, k8 = (id & 15) << 3;
    *(uint4*)&WTl[n * 136 + k8] = v;
  }
  __syncthreads();

  const int lane = tid & 63, wl = tid >> 6;
  const int col = lane & 15, g = lane >> 4;
  const int nb = bx * 64 + wl * 16;
  const int node = nb + col;
  const bool ok = node < N;

  const int arow = min(node, N - 1);
  const float* xr = x + (size_t)arow * 128;
  bf16x8 xh[4], xlo[4];
#pragma unroll
  for (int t = 0; t < 4; ++t) {
    float4 u = *(const float4*)&xr[t * 32 + g * 8];
    float4 v = *(const float4*)&xr[t * 32 + g * 8 + 4];
    float e[8] = {u.x, u.y, u.z, u.w, v.x, v.y, v.z, v.w};
    bf16x8 h8, l8;
#pragma unroll
    for (int j = 0; j < 8; ++j) {
      u16 hbt = f2bf(e[j]);
      h8[j] = (short)hbt;
      l8[j] = (short)f2bf(e[j] - bf2f(hbt));
    }
    xh[t] = h8; xlo[t] = l8;
  }

  f32x4 acc[8];
#pragma unroll
  for (int c = 0; c < 8; ++c) {
    float4 bv = *(const float4*)&bias[c * 16 + g * 4];
    acc[c] = (f32x4){bv.x, bv.y, bv.z, bv.w};
  }

#pragma unroll
  for (int c = 0; c < 8; ++c) {
    const u16* wrow = &WTl[(c * 16 + col) * 136];
#pragma unroll
    for (int t = 0; t < 4; ++t) {
      bf16x8 wf = *(const bf16x8*)&wrow[t * 32 + g * 8];
      acc[c] = __builtin_amdgcn_mfma_f32_16x16x32_bf16(wf, xh[t],  acc[c], 0, 0, 0);
      acc[c] = __builtin_amdgcn_mfma_f32_16x16x32_bf16(wf, xlo[t], acc[c], 0, 0, 0);
    }
  }

  if (ok) {
#pragma unroll
    for (int c = 0; c < 8; ++c) {
      uint2 hv;
      hv.x = (u32)f2bf(acc[c][0]) | ((u32)f2bf(acc[c][1]) << 16);
      hv.y = (u32)f2bf(acc[c][2]) | ((u32)f2bf(acc[c][3]) << 16);
      *(uint2*)(h_out + (size_t)node * 128 + c * 16 + g * 4) = hv;
    }
  }

#pragma unroll
  for (int c = 0; c < 8; ++c) {
    float4 a0v = *(const float4*)&att0[c * 16 + g * 4];
    float4 a1v = *(const float4*)&att1[c * 16 + g * 4];
    float4 a2v = *(const float4*)&att2[c * 16 + g * 4];
    float4 a3v = *(const float4*)&att3[c * 16 + g * 4];
    float p0 = acc[c][0] * a0v.x + acc[c][1] * a0v.y + acc[c][2] * a0v.z + acc[c][3] * a0v.w;
    float p1 = acc[c][0] * a1v.x + acc[c][1] * a1v.y + acc[c][2] * a1v.z + acc[c][3] * a1v.w;
    float p2 = acc[c][0] * a2v.x + acc[c][1] * a2v.y + acc[c][2] * a2v.z + acc[c][3] * a2v.w;
    float p3 = acc[c][0] * a3v.x + acc[c][1] * a3v.y + acc[c][2] * a3v.z + acc[c][3] * a3v.w;
    p0 += __shfl_xor(p0, 16); p0 += __shfl_xor(p0, 32);
    p1 += __shfl_xor(p1, 16); p1 += __shfl_xor(p1, 32);
    p2 += __shfl_xor(p2, 16); p2 += __shfl_xor(p2, 32);
    p3 += __shfl_xor(p3, 16); p3 += __shfl_xor(p3, 32);
    if (ok && g == 0) {
      al0[node * 8 + c] = p0;
      al1[node * 8 + c] = p1;
      al2[node * 8 + c] = p2;
      al3[node * 8 + c] = p3;
    }
  }
}

// ------------------------- CSR scans + scatter -----------------------------
__global__ __launch_bounds__(256) void scan1_kernel(int* __restrict__ data, int M,
                                                    int* __restrict__ bsum)
{
  __shared__ int ls[256];
  const int tid = threadIdx.x;
  const int base = blockIdx.x * 2048 + tid * 8;
  int v[8]; int s = 0;
#pragma unroll
  for (int j = 0; j < 8; ++j) v[j] = (base + j < M) ? data[base + j] : 0;
#pragma unroll
  for (int j = 0; j < 8; ++j) { int t = v[j]; v[j] = s; s += t; }
  ls[tid] = s;
  __syncthreads();
  for (int off = 1; off < 256; off <<= 1) {
    int t = (tid >= off) ? ls[tid - off] : 0;
    __syncthreads();
    ls[tid] += t;
    __syncthreads();
  }
  int texcl = ls[tid] - s;
#pragma unroll
  for (int j = 0; j < 8; ++j)
    if (base + j < M) data[base + j] = v[j] + texcl;
  if (tid == 255) bsum[blockIdx.x] = ls[255];
}

// scan3: block computes its own prefix over bsum (G1 <= 256), adds, mirrors.
__global__ __launch_bounds__(256) void scan3_kernel(int* __restrict__ data,
                                                    const int* __restrict__ bsum, int M,
                                                    int* __restrict__ cursor)
{
  __shared__ int rs[4];
  const int tid = threadIdx.x;
  int v = (tid < (int)blockIdx.x) ? bsum[tid] : 0;   // tid<bid<=G1-1 -> in range
#pragma unroll
  for (int off = 32; off > 0; off >>= 1) v += __shfl_down(v, off);
  if ((tid & 63) == 0) rs[tid >> 6] = v;
  __syncthreads();
  const int add = rs[0] + rs[1] + rs[2] + rs[3];
  const int base = blockIdx.x * 2048 + tid * 8;
#pragma unroll
  for (int j = 0; j < 8; ++j) {
    int i = base + j;
    if (i < M) { int t = data[i] + add; data[i] = t; cursor[i] = t; }
  }
}

__global__ __launch_bounds__(256) void scatter_kernel(
    const int* __restrict__ e0, const int* __restrict__ e1,
    const int* __restrict__ e2, const int* __restrict__ e3,
    int E, int N, int* __restrict__ cursor, int* __restrict__ ssrc)
{
  const int r = blockIdx.y;
  const int* ei = (r == 0) ? e0 : (r == 1) ? e1 : (r == 2) ? e2 : e3;
  int e = blockIdx.x * 256 + threadIdx.x;
  if (e >= E) return;
  int s = ei[e], d = ei[E + e];
  int p = atomicAdd(&cursor[r * N + d], 1);
  ssrc[p] = s;
}

// ---------------------------------------------------------------------------
// Fused segment-softmax + aggregate: 1 wave per dst node, 4-edge chunks.
// Output: relu(o) packed bf16.
// ---------------------------------------------------------------------------
__global__ __launch_bounds__(256) void aggregate_kernel(
    const int* __restrict__ off, const int* __restrict__ ssrc,
    const float* __restrict__ aS0, const float* __restrict__ aS1,
    const float* __restrict__ aS2, const float* __restrict__ aS3,
    const float* __restrict__ aD0, const float* __restrict__ aD1,
    const float* __restrict__ aD2, const float* __restrict__ aD3,
    const u16* __restrict__ h0, const u16* __restrict__ h1,
    const u16* __restrict__ h2, const u16* __restrict__ h3,
    u32* __restrict__ o0, u32* __restrict__ o1,
    u32* __restrict__ o2, u32* __restrict__ o3,
    int N, int E)
{
  const int r = blockIdx.y;
  const float* aS = (r == 0) ? aS0 : (r == 1) ? aS1 : (r == 2) ? aS2 : aS3;
  const float* aD = (r == 0) ? aD0 : (r == 1) ? aD1 : (r == 2) ? aD2 : aD3;
  const u16*   h  = (r == 0) ? h0  : (r == 1) ? h1  : (r == 2) ? h2  : h3;
  u32*         o  = (r == 0) ? o0  : (r == 1) ? o1  : (r == 2) ? o2  : o3;

  const int wave = threadIdx.x >> 6, lane = threadIdx.x & 63;
  const int n = blockIdx.x * 4 + wave;
  if (n >= N) return;
  const int head = lane >> 3;
  const int idx = r * N + n;
  const int p0 = off[idx];
  const int p1 = (idx + 1 < 4 * N) ? off[idx + 1] : 4 * E;
  const float aDv = aD[n * 8 + head];
  const u32* h32 = (const u32*)h;

  float acc0 = 0.f, acc1 = 0.f, den = 0.f;
  int p = p0;
  for (; p + 4 <= p1; p += 4) {
    const int s0 = ssrc[p], s1 = ssrc[p + 1], s2 = ssrc[p + 2], s3 = ssrc[p + 3];
    const float g0 = aS[s0 * 8 + head];
    const float g1 = aS[s1 * 8 + head];
    const float g2 = aS[s2 * 8 + head];
    const float g3 = aS[s3 * 8 + head];
    const u32 v0 = h32[s0 * 64 + lane];
    const u32 v1 = h32[s1 * 64 + lane];
    const u32 v2 = h32[s2 * 64 + lane];
    const u32 v3 = h32[s3 * 64 + lane];
    float l0 = g0 + aDv, l1 = g1 + aDv, l2 = g2 + aDv, l3 = g3 + aDv;
    l0 = fmaxf(l0, 0.2f * l0); l1 = fmaxf(l1, 0.2f * l1);
    l2 = fmaxf(l2, 0.2f * l2); l3 = fmaxf(l3, 0.2f * l3);
    const float w0 = __expf(l0), w1 = __expf(l1);
    const float w2 = __expf(l2), w3 = __expf(l3);
    den += (w0 + w1) + (w2 + w3);
    acc0 += w0 * blo(v0) + w1 * blo(v1) + w2 * blo(v2) + w3 * blo(v3);
    acc1 += w0 * bhi(v0) + w1 * bhi(v1) + w2 * bhi(v2) + w3 * bhi(v3);
  }
  const int rem = p1 - p;
  if (rem > 0) {
    const int s0 = ssrc[p];
    const int s1 = ssrc[(rem > 1) ? p + 1 : p];
    const int s2 = ssrc[(rem > 2) ? p + 2 : p];
    const float g0 = aS[s0 * 8 + head];
    const float g1 = aS[s1 * 8 + head];
    const float g2 = aS[s2 * 8 + head];
    const u32 v0 = h32[s0 * 64 + lane];
    const u32 v1 = h32[s1 * 64 + lane];
    const u32 v2 = h32[s2 * 64 + lane];
    float l0 = g0 + aDv, l1 = g1 + aDv, l2 = g2 + aDv;
    l0 = fmaxf(l0, 0.2f * l0); l1 = fmaxf(l1, 0.2f * l1); l2 = fmaxf(l2, 0.2f * l2);
    const float w0 = __expf(l0);
    const float w1 = (rem > 1) ? __expf(l1) : 0.f;
    const float w2 = (rem > 2) ? __expf(l2) : 0.f;
    den += w0 + w1 + w2;
    acc0 += w0 * blo(v0) + w1 * blo(v1) + w2 * blo(v2);
    acc1 += w0 * bhi(v0) + w1 * bhi(v1) + w2 * bhi(v2);
  }
  const float inv = 1.f / (den + 1e-16f);
  const float r0 = fmaxf(acc0 * inv, 0.f);
  const float r1 = fmaxf(acc1 * inv, 0.f);
  o[n * 64 + lane] = (u32)f2bf(r0) | ((u32)f2bf(r1) << 16);
}

// ---------------------------------------------------------------------------
// K2: fused {bn 5-moment stats (attn-independent) | MFMA semantic score}.
// sem stages WkT into LDS via uint4 (off the L2 latency path); stats blocks
// reuse the same LDS as scratch.
// ---------------------------------------------------------------------------
__global__ __launch_bounds__(256) void fused2_kernel(
    const u32* __restrict__ oba, const u32* __restrict__ oaa,
    const u32* __restrict__ oab, const u32* __restrict__ obb,
    const u16* __restrict__ WkT, const float* __restrict__ bk,
    const float* __restrict__ q, float* __restrict__ scores,
    float* __restrict__ sums_a, float* __restrict__ sums_b,
    int N, int R, int gproj)
{
  __shared__ __align__(16) u16 WTl[128 * 136];
  __shared__ float red[4];
  const int tid = threadIdx.x;
  const int bid = blockIdx.x;

  if (bid < 512) {                       // ---- bn 5-moment stats ----
    const int t = bid >> 8, bx = bid & 255;
    const u32* p0 = t ? oab : oba;
    const u32* p1 = t ? obb : oaa;
    float* sums = t ? sums_b : sums_a;
    const int tc = tid & 31, tr = tid >> 5;
    float s0[4] = {0,0,0,0}, s1[4] = {0,0,0,0};
    float q00[4] = {0,0,0,0}, q11[4] = {0,0,0,0}, q01[4] = {0,0,0,0};
    const int rend = min((bx + 1) * R, N);
    for (int row = bx * R + tr; row < rend; row += 8) {
      uint2 v0 = *(const uint2*)&p0[row * 64 + tc * 2];
      uint2 v1 = *(const uint2*)&p1[row * 64 + tc * 2];
      float r0[4] = {blo(v0.x), bhi(v0.x), blo(v0.y), bhi(v0.y)};
      float r1[4] = {blo(v1.x), bhi(v1.x), blo(v1.y), bhi(v1.y)};
#pragma unroll
      for (int j = 0; j < 4; ++j) {
        s0[j] += r0[j]; s1[j] += r1[j];
        q00[j] += r0[j] * r0[j]; q11[j] += r1[j] * r1[j];
        q01[j] += r0[j] * r1[j];
      }
    }
    float* sm = (float*)WTl;             // reuse LDS: 5 x 128 floats
    for (int i = tid; i < 640; i += 256) sm[i] = 0.f;
    __syncthreads();
#pragma unroll
    for (int j = 0; j < 4; ++j) {
      int f = tc * 4 + j;
      atomicAdd(&sm[f], s0[j]);
      atomicAdd(&sm[128 + f], s1[j]);
      atomicAdd(&sm[256 + f], q00[j]);
      atomicAdd(&sm[384 + f], q11[j]);
      atomicAdd(&sm[512 + f], q01[j]);
    }
    __syncthreads();
    for (int i = tid; i < 640; i += 256) atomicAdd(&sums[i], sm[i]);
    return;
  }

  // ---- sem_score ----
  const int sid = bid - 512;
  const int rel = sid & 3, bx = sid >> 2;
  const u32* op = (rel == 0) ? oba : (rel == 1) ? oaa : (rel == 2) ? oab : obb;
  const u16* o = (const u16*)op;

  // stage WkT -> LDS (aligned uint4, no conversion)
  const uint4* Wg = (const uint4*)WkT;
#pragma unroll
  for (int i = 0; i < 8; ++i) {
    int id = tid + 256 * i;
    uint4 v = Wg[id];
    int n = id >> 4, k8 = (id & 15) << 3;
    *(uint4*)&WTl[n * 136 + k8] = v;
  }
  __syncthreads();

  const int lane = tid & 63, wl = tid >> 6;
  const int col = lane & 15, g = lane >> 4;
  const int nb = bx * 64 + wl * 16;

  float bv[8], qv[8];
#pragma unroll
  for (int c = 0; c < 8; ++c) {
    bv[c] = bk[c * 16 + col];
    qv[c] = q[c * 16 + col];
  }

  const int arow = min(nb + col, N - 1);
  const u16* orow = o + (size_t)arow * 128;
  bf16x8 af[4];
#pragma unroll
  for (int t = 0; t < 4; ++t) af[t] = *(const bf16x8*)&orow[t * 32 + g * 8];

  f32x4 acc[8];
#pragma unroll
  for (int c = 0; c < 8; ++c) acc[c] = (f32x4){bv[c], bv[c], bv[c], bv[c]};

#pragma unroll
  for (int c = 0; c < 8; ++c) {
    const u16* wrow = &WTl[(c * 16 + col) * 136];
#pragma unroll
    for (int t = 0; t < 4; ++t) {
      bf16x8 bf = *(const bf16x8*)&wrow[t * 32 + g * 8];
      acc[c] = __builtin_amdgcn_mfma_f32_16x16x32_bf16(af[t], bf, acc[c], 0, 0, 0);
    }
  }

  float p = 0.f;
  const int rowbase = nb + g * 4;
#pragma unroll
  for (int c = 0; c < 8; ++c) {
#pragma unroll
    for (int i = 0; i < 4; ++i) {
      int node = rowbase + i;
      if (node < N) p += fast_tanh(acc[c][i]) * qv[c];
    }
  }
#pragma unroll
  for (int off = 32; off > 0; off >>= 1) p += __shfl_down(p, off);
  if (lane == 0) red[wl] = p;
  __syncthreads();
  if (tid == 0) atomicAdd(&scores[rel], red[0] + red[1] + red[2] + red[3]);
}

// ---------------------------------------------------------------------------
// bn_final: inline semantic softmax + moment combine + normalize + write.
// ---------------------------------------------------------------------------
__global__ __launch_bounds__(256) void bn_final_kernel(
    const u32* __restrict__ oba, const u32* __restrict__ oaa,
    const u32* __restrict__ oab, const u32* __restrict__ obb,
    const float* __restrict__ scores, const float* __restrict__ sums_a,
    const float* __restrict__ sums_b,
    const float* __restrict__ gamma, const float* __restrict__ beta,
    float* __restrict__ out, int N)
{
  const int t = blockIdx.y;
  const u32* o0 = t ? oab : oba;
  const u32* o1 = t ? obb : oaa;
  const float* sums = t ? sums_b : sums_a;
  float* op = out + (size_t)t * N * 128;

  const float invN = 1.f / (float)N;
  const float sc0 = scores[2 * t] * invN, sc1 = scores[2 * t + 1] * invN;
  const float m = fmaxf(sc0, sc1);
  const float e0 = expf(sc0 - m), e1 = expf(sc1 - m);
  const float einv = 1.f / (e0 + e1);
  const float a0 = e0 * einv, a1 = e1 * einv;

  __shared__ float scale[128], shift[128];
  if (threadIdx.x < 128) {
    int f = threadIdx.x;
    float S0 = sums[f], S1 = sums[128 + f];
    float Q00 = sums[256 + f], Q11 = sums[384 + f], Q01 = sums[512 + f];
    float mu = (a0 * S0 + a1 * S1) * invN;
    float msq = (a0 * a0 * Q00 + 2.f * a0 * a1 * Q01 + a1 * a1 * Q11) * invN;
    float var = fmaxf(msq - mu * mu, 0.f);
    float rs = rsqrtf(var + 1e-5f);
    float gm = gamma[f] * rs;
    scale[f] = gm;
    shift[f] = beta[f] - mu * gm;
  }
  __syncthreads();
  size_t total = (size_t)N * 128;
  for (size_t base = ((size_t)blockIdx.x * 256 + threadIdx.x) * 8; base < total;
       base += (size_t)gridDim.x * 2048) {
    int f0 = (int)(base & 127);
    uint4 p = *(const uint4*)&o0[base >> 1];
    uint4 q = *(const uint4*)&o1[base >> 1];
    float4 r0, r1;
    r0.x = (a0 * blo(p.x) + a1 * blo(q.x)) * scale[f0 + 0] + shift[f0 + 0];
    r0.y = (a0 * bhi(p.x) + a1 * bhi(q.x)) * scale[f0 + 1] + shift[f0 + 1];
    r0.z = (a0 * blo(p.y) + a1 * blo(q.y)) * scale[f0 + 2] + shift[f0 + 2];
    r0.w = (a0 * bhi(p.y) + a1 * bhi(q.y)) * scale[f0 + 3] + shift[f0 + 3];
    r1.x = (a0 * blo(p.z) + a1 * blo(q.z)) * scale[f0 + 4] + shift[f0 + 4];
    r1.y = (a0 * bhi(p.z) + a1 * bhi(q.z)) * scale[f0 + 5] + shift[f0 + 5];
    r1.z = (a0 * blo(p.w) + a1 * blo(q.w)) * scale[f0 + 6] + shift[f0 + 6];
    r1.w = (a0 * bhi(p.w) + a1 * bhi(q.w)) * scale[f0 + 7] + shift[f0 + 7];
    *(float4*)&op[base] = r0;
    *(float4*)&op[base + 4] = r1;
  }
}

extern "C" void kernel_launch(void* const* d_in, const int* in_sizes, int n_in,
                              void* d_out, int out_size, void* d_ws, size_t ws_size,
                              hipStream_t stream)
{
  const float* x_a      = (const float*)d_in[0];
  const float* x_b      = (const float*)d_in[1];
  const int* ei_ab      = (const int*)d_in[2];
  const int* ei_ba      = (const int*)d_in[3];
  const int* ei_aa      = (const int*)d_in[4];
  const int* ei_bb      = (const int*)d_in[5];
  const float* W_a      = (const float*)d_in[6];
  const float* b_a      = (const float*)d_in[7];
  const float* W_b      = (const float*)d_in[8];
  const float* b_b      = (const float*)d_in[9];
  const float* att_ab_s = (const float*)d_in[10];
  const float* att_ab_d = (const float*)d_in[11];
  const float* att_ba_s = (const float*)d_in[12];
  const float* att_ba_d = (const float*)d_in[13];
  const float* att_aa_s = (const float*)d_in[14];
  const float* att_aa_d = (const float*)d_in[15];
  const float* att_bb_s = (const float*)d_in[16];
  const float* att_bb_d = (const float*)d_in[17];
  const float* Wk       = (const float*)d_in[18];
  const float* bk       = (const float*)d_in[19];
  const float* q        = (const float*)d_in[20];
  const float* gamma    = (const float*)d_in[21];
  const float* beta     = (const float*)d_in[22];

  const int N = in_sizes[0] / 128;
  const int E = in_sizes[2] / 2;

  char* wp = (char*)d_ws;
  auto alloc = [&](size_t bytes) -> void* {
    void* p = (void*)wp;
    wp += (bytes + 255) & ~(size_t)255;
    return p;
  };
  u16* h_a = (u16*)alloc((size_t)N * 128 * 2);
  u16* h_b = (u16*)alloc((size_t)N * 128 * 2);
  float* A[8];
  for (int i = 0; i < 8; ++i) A[i] = (float*)alloc((size_t)N * 8 * 4);
  int* off    = (int*)alloc((size_t)4 * N * 4);
  int* cursor = (int*)alloc((size_t)4 * N * 4);
  int* bsum   = (int*)alloc(1024);
  int* ssrc   = (int*)alloc((size_t)4 * E * 4);
  u32* o_ab = (u32*)alloc((size_t)N * 64 * 4);   // packed relu bf16
  u32* o_ba = (u32*)alloc((size_t)N * 64 * 4);
  u32* o_aa = (u32*)alloc((size_t)N * 64 * 4);
  u32* o_bb = (u32*)alloc((size_t)N * 64 * 4);
  float* scores = (float*)alloc(16);             // 256B slot
  float* sums_a = (float*)alloc(2560);           // 5 x 128 f32
  float* sums_b = (float*)alloc(2560);
  u16* WT_a = (u16*)alloc(128 * 128 * 2);
  u16* WT_b = (u16*)alloc(128 * 128 * 2);
  u16* WT_k = (u16*)alloc(128 * 128 * 2);
  if ((size_t)(wp - (char*)d_ws) > ws_size) return;

  hipMemsetAsync(off, 0, (size_t)4 * N * 4, stream);
  hipMemsetAsync(scores, 0, 5376, stream);       // scores+sums_a+sums_b contiguous

  // --- weight prep (W_a, W_b, Wk -> transposed bf16) ---
  dim3 gw(64, 3);
  wprep_kernel<<<gw, 256, 0, stream>>>(W_a, W_b, Wk, WT_a, WT_b, WT_k);

  // --- K1: proj (both types) | hist (4 rel) ---
  // relation order: 0=ab 1=ba 2=aa 3=bb
  // type a att slots: ab_s, aa_s, aa_d, ba_d -> A[0..3]
  // type b att slots: ab_d, bb_s, bb_d, ba_s -> A[4..7]
  const int gproj = (N + 63) / 64;
  const int gE = (E + 255) / 256;
  const int interleave = (gE == gproj) ? 1 : 0;
  const int g1total = 2 * gproj + 4 * gE;
  fused1_kernel<<<g1total, 256, 0, stream>>>(
      x_a, x_b, WT_a, WT_b, b_a, b_b,
      att_ab_s, att_aa_s, att_aa_d, att_ba_d,
      att_ab_d, att_bb_s, att_bb_d, att_ba_s,
      h_a, h_b,
      A[0], A[1], A[2], A[3], A[4], A[5], A[6], A[7],
      ei_ab, ei_ba, ei_aa, ei_bb,
      off, N, E, gproj, gE, interleave);

  // --- CSR scans + scatter (scan2 folded into scan3) ---
  const int M = 4 * N;
  const int G1 = (M + 2047) / 2048;          // <= 256 for N <= 131072
  scan1_kernel<<<G1, 256, 0, stream>>>(off, M, bsum);
  scan3_kernel<<<G1, 256, 0, stream>>>(off, bsum, M, cursor);
  dim3 gsc(gE, 4);
  scatter_kernel<<<gsc, 256, 0, stream>>>(ei_ab, ei_ba, ei_aa, ei_bb, E, N, cursor, ssrc);

  // --- fused softmax + aggregate ---
  dim3 gag((N + 3) / 4, 4);
  aggregate_kernel<<<gag, 256, 0, stream>>>(
      off, ssrc,
      A[0], A[7], A[1], A[5],          // aS per relation: ab,ba,aa,bb
      A[4], A[3], A[2], A[6],          // aD per relation
      h_a, h_b, h_a, h_b,
      o_ab, o_ba, o_aa, o_bb, N, E);

  // --- K2: bn 5-moment stats | semantic scores (slot order ba,aa,ab,bb) ---
  const int R = (N + 255) / 256;
  const int g2total = 512 + 4 * gproj;
  fused2_kernel<<<g2total, 256, 0, stream>>>(
      o_ba, o_aa, o_ab, o_bb, WT_k, bk, q, scores, sums_a, sums_b, N, R, gproj);

  // --- bn_final with inline softmax + moment combine ---
  float* out = (float*)d_out;
  dim3 gbf(1024, 2);
  bn_final_kernel<<<gbf, 256, 0, stream>>>(o_ba, o_aa, o_ab, o_bb, scores,
                                           sums_a, sums_b, gamma, beta, out, N);
}

// Round 11
// 635.341 us; speedup vs baseline: 1.1078x; 1.0025x over previous
//
#include <hip/hip_runtime.h>

using u16 = unsigned short;
using u32 = unsigned int;
using bf16x8 = __attribute__((ext_vector_type(8))) short;
using f32x4  = __attribute__((ext_vector_type(4))) float;

__device__ __forceinline__ float bf2f(u16 v) { return __uint_as_float(((u32)v) << 16); }
__device__ __forceinline__ float blo(u32 u) { return __uint_as_float(u << 16); }
__device__ __forceinline__ float bhi(u32 u) { return __uint_as_float(u & 0xffff0000u); }
__device__ __forceinline__ u16 f2bf(float f) {
  u32 u = __float_as_uint(f);
  u += 0x7fffu + ((u >> 16) & 1u);   // RNE
  return (u16)(u >> 16);
}
__device__ __forceinline__ float fast_tanh(float x) {
  float cx = fminf(fmaxf(x, -9.f), 9.f);
  float e = __expf(2.f * cx);
  return (e - 1.f) / (e + 1.f);
}

// ---------------------------------------------------------------------------
// Weight prep: W (f32 [k][n]) -> WT (bf16 [n][k]) once, for W_a, W_b, Wk.
// Downstream kernels stage WT into LDS with plain uint4 copies (no f2bf,
// conflict-free) — LDS keeps W-frag reads off the L2 latency path.
// ---------------------------------------------------------------------------
__global__ __launch_bounds__(256) void wprep_kernel(
    const float* __restrict__ Wa, const float* __restrict__ Wb,
    const float* __restrict__ Wk,
    u16* __restrict__ Ta, u16* __restrict__ Tb, u16* __restrict__ Tk)
{
  const int w = blockIdx.y;
  const float* W = (w == 0) ? Wa : (w == 1) ? Wb : Wk;
  u16* T = (w == 0) ? Ta : (w == 1) ? Tb : Tk;
  int idx = blockIdx.x * 256 + threadIdx.x;    // 0..16383
  int k = idx >> 7, n = idx & 127;
  T[n * 128 + k] = f2bf(W[idx]);
}

// ---------------------------------------------------------------------------
// K1: fused {proj (both types, WT uint4-staged in LDS) | hist (4 rel)}.
// Interleave [proj,hist,hist] (gE==gproj when E==4N) so MFMA blocks co-reside
// with atomic-latency hist blocks on each CU.
// proj: D = WT-frag (A) x x-frag (B) = h^T tile; lane (col,g) holds feats
// c*16+4g+{0..3} of node nb+col; x split hi/lo bf16.
// ---------------------------------------------------------------------------
__global__ __launch_bounds__(256) void fused1_kernel(
    const float* __restrict__ x_a, const float* __restrict__ x_b,
    const u16* __restrict__ WTa, const u16* __restrict__ WTb,
    const float* __restrict__ b_a, const float* __restrict__ b_b,
    const float* __restrict__ at0a, const float* __restrict__ at1a,
    const float* __restrict__ at2a, const float* __restrict__ at3a,
    const float* __restrict__ at0b, const float* __restrict__ at1b,
    const float* __restrict__ at2b, const float* __restrict__ at3b,
    u16* __restrict__ ha, u16* __restrict__ hb,
    float* __restrict__ a0a, float* __restrict__ a1a,
    float* __restrict__ a2a, float* __restrict__ a3a,
    float* __restrict__ a0b, float* __restrict__ a1b,
    float* __restrict__ a2b, float* __restrict__ a3b,
    const int* __restrict__ e0, const int* __restrict__ e1,
    const int* __restrict__ e2, const int* __restrict__ e3,
    int* __restrict__ cnt,
    int N, int E, int gproj, int gE, int interleave)
{
  __shared__ __align__(16) u16 WTl[128 * 136];
  const int tid = threadIdx.x;
  const int bid = blockIdx.x;
  const int nP = 2 * gproj;

  int role, idx;
  if (interleave) {
    int slot = bid % 3, grp = bid / 3;
    if (slot == 0) { role = 0; idx = grp; }
    else           { role = 1; idx = grp * 2 + slot - 1; }
  } else {
    if (bid < nP) { role = 0; idx = bid; }
    else          { role = 1; idx = bid - nP; }
  }

  if (role == 1) {                 // ---- hist ----
    const int r = idx & 3, ex = idx >> 2;
    const int* ei = (r == 0) ? e0 : (r == 1) ? e1 : (r == 2) ? e2 : e3;
    int e = ex * 256 + tid;
    if (e < E) atomicAdd(&cnt[r * N + ei[E + e]], 1);
    return;
  }

  // ---- proj ----
  const int ty = idx >= gproj;
  const int bx = idx - (ty ? gproj : 0);
  const float* x    = ty ? x_b : x_a;
  const u16*  WT    = ty ? WTb : WTa;
  const float* bias = ty ? b_b : b_a;
  const float* att0 = ty ? at0b : at0a;
  const float* att1 = ty ? at1b : at1a;
  const float* att2 = ty ? at2b : at2a;
  const float* att3 = ty ? at3b : at3a;
  u16* h_out = ty ? hb : ha;
  float* al0 = ty ? a0b : a0a;
  float* al1 = ty ? a1b : a1a;
  float* al2 = ty ? a2b : a2a;
  float* al3 = ty ? a3b : a3a;

  // stage WT -> LDS with aligned uint4 copies (no conversion, conflict-free)
  const uint4* Wg = (const uint4*)WT;          // 2048 x 16B
#pragma unroll
  for (int i = 0; i < 8; ++i) {
    int id = tid + 256 * i;                    // n = id>>4, k8 = (id&15)*8
    uint4 v = Wg[id];
    int n = id >> 4, k8 = (id & 15) << 3;
    *(uint4*)&WTl[n * 136 + k8] = v;
  }
  __syncthreads();

  const int lane = tid & 63, wl = tid >> 6;
  const int col = lane & 15, g = lane >> 4;
  const int nb = bx * 64 + wl * 16;
  const int node = nb + col;
  const bool ok = node < N;

  const int arow = min(node, N - 1);
  const float* xr = x + (size_t)arow * 128;
  bf16x8 xh[4], xlo[4];
#pragma unroll
  for (int t = 0; t < 4; ++t) {
    float4 u = *(const float4*)&xr[t * 32 + g * 8];
    float4 v = *(const float4*)&xr[t * 32 + g * 8 + 4];
    float e[8] = {u.x, u.y, u.z, u.w, v.x, v.y, v.z, v.w};
    bf16x8 h8, l8;
#pragma unroll
    for (int j = 0; j < 8; ++j) {
      u16 hbt = f2bf(e[j]);
      h8[j] = (short)hbt;
      l8[j] = (short)f2bf(e[j] - bf2f(hbt));
    }
    xh[t] = h8; xlo[t] = l8;
  }

  f32x4 acc[8];
#pragma unroll
  for (int c = 0; c < 8; ++c) {
    float4 bv = *(const float4*)&bias[c * 16 + g * 4];
    acc[c] = (f32x4){bv.x, bv.y, bv.z, bv.w};
  }

#pragma unroll
  for (int c = 0; c < 8; ++c) {
    const u16* wrow = &WTl[(c * 16 + col) * 136];
#pragma unroll
    for (int t = 0; t < 4; ++t) {
      bf16x8 wf = *(const bf16x8*)&wrow[t * 32 + g * 8];
      acc[c] = __builtin_amdgcn_mfma_f32_16x16x32_bf16(wf, xh[t],  acc[c], 0, 0, 0);
      acc[c] = __builtin_amdgcn_mfma_f32_16x16x32_bf16(wf, xlo[t], acc[c], 0, 0, 0);
    }
  }

  if (ok) {
#pragma unroll
    for (int c = 0; c < 8; ++c) {
      uint2 hv;
      hv.x = (u32)f2bf(acc[c][0]) | ((u32)f2bf(acc[c][1]) << 16);
      hv.y = (u32)f2bf(acc[c][2]) | ((u32)f2bf(acc[c][3]) << 16);
      *(uint2*)(h_out + (size_t)node * 128 + c * 16 + g * 4) = hv;
    }
  }

#pragma unroll
  for (int c = 0; c < 8; ++c) {
    float4 a0v = *(const float4*)&att0[c * 16 + g * 4];
    float4 a1v = *(const float4*)&att1[c * 16 + g * 4];
    float4 a2v = *(const float4*)&att2[c * 16 + g * 4];
    float4 a3v = *(const float4*)&att3[c * 16 + g * 4];
    float p0 = acc[c][0] * a0v.x + acc[c][1] * a0v.y + acc[c][2] * a0v.z + acc[c][3] * a0v.w;
    float p1 = acc[c][0] * a1v.x + acc[c][1] * a1v.y + acc[c][2] * a1v.z + acc[c][3] * a1v.w;
    float p2 = acc[c][0] * a2v.x + acc[c][1] * a2v.y + acc[c][2] * a2v.z + acc[c][3] * a2v.w;
    float p3 = acc[c][0] * a3v.x + acc[c][1] * a3v.y + acc[c][2] * a3v.z + acc[c][3] * a3v.w;
    p0 += __shfl_xor(p0, 16); p0 += __shfl_xor(p0, 32);
    p1 += __shfl_xor(p1, 16); p1 += __shfl_xor(p1, 32);
    p2 += __shfl_xor(p2, 16); p2 += __shfl_xor(p2, 32);
    p3 += __shfl_xor(p3, 16); p3 += __shfl_xor(p3, 32);
    if (ok && g == 0) {
      al0[node * 8 + c] = p0;
      al1[node * 8 + c] = p1;
      al2[node * 8 + c] = p2;
      al3[node * 8 + c] = p3;
    }
  }
}

// ------------------------- CSR scans + scatter -----------------------------
__global__ __launch_bounds__(256) void scan1_kernel(int* __restrict__ data, int M,
                                                    int* __restrict__ bsum)
{
  __shared__ int ls[256];
  const int tid = threadIdx.x;
  const int base = blockIdx.x * 2048 + tid * 8;
  int v[8]; int s = 0;
#pragma unroll
  for (int j = 0; j < 8; ++j) v[j] = (base + j < M) ? data[base + j] : 0;
#pragma unroll
  for (int j = 0; j < 8; ++j) { int t = v[j]; v[j] = s; s += t; }
  ls[tid] = s;
  __syncthreads();
  for (int off = 1; off < 256; off <<= 1) {
    int t = (tid >= off) ? ls[tid - off] : 0;
    __syncthreads();
    ls[tid] += t;
    __syncthreads();
  }
  int texcl = ls[tid] - s;
#pragma unroll
  for (int j = 0; j < 8; ++j)
    if (base + j < M) data[base + j] = v[j] + texcl;
  if (tid == 255) bsum[blockIdx.x] = ls[255];
}

// scan3: block computes its own prefix over bsum (G1 <= 256), adds, mirrors.
__global__ __launch_bounds__(256) void scan3_kernel(int* __restrict__ data,
                                                    const int* __restrict__ bsum, int M,
                                                    int* __restrict__ cursor)
{
  __shared__ int rs[4];
  const int tid = threadIdx.x;
  int v = (tid < (int)blockIdx.x) ? bsum[tid] : 0;   // tid<bid<=G1-1 -> in range
#pragma unroll
  for (int off = 32; off > 0; off >>= 1) v += __shfl_down(v, off);
  if ((tid & 63) == 0) rs[tid >> 6] = v;
  __syncthreads();
  const int add = rs[0] + rs[1] + rs[2] + rs[3];
  const int base = blockIdx.x * 2048 + tid * 8;
#pragma unroll
  for (int j = 0; j < 8; ++j) {
    int i = base + j;
    if (i < M) { int t = data[i] + add; data[i] = t; cursor[i] = t; }
  }
}

__global__ __launch_bounds__(256) void scatter_kernel(
    const int* __restrict__ e0, const int* __restrict__ e1,
    const int* __restrict__ e2, const int* __restrict__ e3,
    int E, int N, int* __restrict__ cursor, int* __restrict__ ssrc)
{
  const int r = blockIdx.y;
  const int* ei = (r == 0) ? e0 : (r == 1) ? e1 : (r == 2) ? e2 : e3;
  int e = blockIdx.x * 256 + threadIdx.x;
  if (e >= E) return;
  int s = ei[e], d = ei[E + e];
  int p = atomicAdd(&cursor[r * N + d], 1);
  ssrc[p] = s;
}

// ---------------------------------------------------------------------------
// Fused segment-softmax + aggregate: 1 wave per dst node, 4-edge chunks.
// Weight dedup: the softmax weight is per-(edge,head) (8 lanes/head used to
// compute it redundantly, incl. the 1/4-rate exp). Now lane l computes the
// weight for (edge l&3, head (l>>2)&7) — 32 distinct pairs — and each lane
// collects its head's 4 weights via __shfl. Bitwise-identical results.
// Output: relu(o) packed bf16.
// ---------------------------------------------------------------------------
__global__ __launch_bounds__(256) void aggregate_kernel(
    const int* __restrict__ off, const int* __restrict__ ssrc,
    const float* __restrict__ aS0, const float* __restrict__ aS1,
    const float* __restrict__ aS2, const float* __restrict__ aS3,
    const float* __restrict__ aD0, const float* __restrict__ aD1,
    const float* __restrict__ aD2, const float* __restrict__ aD3,
    const u16* __restrict__ h0, const u16* __restrict__ h1,
    const u16* __restrict__ h2, const u16* __restrict__ h3,
    u32* __restrict__ o0, u32* __restrict__ o1,
    u32* __restrict__ o2, u32* __restrict__ o3,
    int N, int E)
{
  const int r = blockIdx.y;
  const float* aS = (r == 0) ? aS0 : (r == 1) ? aS1 : (r == 2) ? aS2 : aS3;
  const float* aD = (r == 0) ? aD0 : (r == 1) ? aD1 : (r == 2) ? aD2 : aD3;
  const u16*   h  = (r == 0) ? h0  : (r == 1) ? h1  : (r == 2) ? h2  : h3;
  u32*         o  = (r == 0) ? o0  : (r == 1) ? o1  : (r == 2) ? o2  : o3;

  const int wave = threadIdx.x >> 6, lane = threadIdx.x & 63;
  const int n = blockIdx.x * 4 + wave;
  if (n >= N) return;
  const int head = lane >> 3;          // head whose o-row this lane accumulates
  const int hw = (lane >> 2) & 7;      // head whose weight this lane computes
  const int ew = lane & 3;             // edge slot whose weight this lane computes
  const int srcb = head * 4;           // shuffle source base for my head
  const int idx = r * N + n;
  const int p0 = off[idx];
  const int p1 = (idx + 1 < 4 * N) ? off[idx + 1] : 4 * E;
  const float aDw = aD[n * 8 + hw];
  const u32* h32 = (const u32*)h;

  float acc0 = 0.f, acc1 = 0.f, den = 0.f;
  int p = p0;
  for (; p + 4 <= p1; p += 4) {
    const int s0 = ssrc[p], s1 = ssrc[p + 1], s2 = ssrc[p + 2], s3 = ssrc[p + 3];
    // my assigned edge's src (select from the already-loaded wave-uniform s's)
    const int sw = (ew & 1) ? ((ew & 2) ? s3 : s1) : ((ew & 2) ? s2 : s0);
    float lw = aS[sw * 8 + hw] + aDw;
    lw = fmaxf(lw, 0.2f * lw);
    const float wme = __expf(lw);
    const float w0 = __shfl(wme, srcb + 0);
    const float w1 = __shfl(wme, srcb + 1);
    const float w2 = __shfl(wme, srcb + 2);
    const float w3 = __shfl(wme, srcb + 3);
    const u32 v0 = h32[s0 * 64 + lane];
    const u32 v1 = h32[s1 * 64 + lane];
    const u32 v2 = h32[s2 * 64 + lane];
    const u32 v3 = h32[s3 * 64 + lane];
    den += (w0 + w1) + (w2 + w3);
    acc0 += w0 * blo(v0) + w1 * blo(v1) + w2 * blo(v2) + w3 * blo(v3);
    acc1 += w0 * bhi(v0) + w1 * bhi(v1) + w2 * bhi(v2) + w3 * bhi(v3);
  }
  const int rem = p1 - p;
  if (rem > 0) {
    const int s0 = ssrc[p];
    const int s1 = ssrc[(rem > 1) ? p + 1 : p];
    const int s2 = ssrc[(rem > 2) ? p + 2 : p];
    const int swi = (ew < rem) ? ew : 0;   // clamp my edge slot
    const int sw = (swi == 0) ? s0 : (swi == 1) ? s1 : s2;
    float lw = aS[sw * 8 + hw] + aDw;
    lw = fmaxf(lw, 0.2f * lw);
    const float wme = __expf(lw);
    const float w0 = __shfl(wme, srcb + 0);
    float w1 = __shfl(wme, srcb + 1);
    float w2 = __shfl(wme, srcb + 2);
    w1 = (rem > 1) ? w1 : 0.f;
    w2 = (rem > 2) ? w2 : 0.f;
    const u32 v0 = h32[s0 * 64 + lane];
    const u32 v1 = h32[s1 * 64 + lane];
    const u32 v2 = h32[s2 * 64 + lane];
    den += w0 + w1 + w2;
    acc0 += w0 * blo(v0) + w1 * blo(v1) + w2 * blo(v2);
    acc1 += w0 * bhi(v0) + w1 * bhi(v1) + w2 * bhi(v2);
  }
  const float inv = 1.f / (den + 1e-16f);
  const float r0 = fmaxf(acc0 * inv, 0.f);
  const float r1 = fmaxf(acc1 * inv, 0.f);
  o[n * 64 + lane] = (u32)f2bf(r0) | ((u32)f2bf(r1) << 16);
}

// ---------------------------------------------------------------------------
// K2: fused {bn 5-moment stats (attn-independent) | MFMA semantic score}.
// sem stages WkT into LDS via uint4; stats blocks reuse the LDS as scratch.
// ---------------------------------------------------------------------------
__global__ __launch_bounds__(256) void fused2_kernel(
    const u32* __restrict__ oba, const u32* __restrict__ oaa,
    const u32* __restrict__ oab, const u32* __restrict__ obb,
    const u16* __restrict__ WkT, const float* __restrict__ bk,
    const float* __restrict__ q, float* __restrict__ scores,
    float* __restrict__ sums_a, float* __restrict__ sums_b,
    int N, int R, int gproj)
{
  __shared__ __align__(16) u16 WTl[128 * 136];
  __shared__ float red[4];
  const int tid = threadIdx.x;
  const int bid = blockIdx.x;

  if (bid < 512) {                       // ---- bn 5-moment stats ----
    const int t = bid >> 8, bx = bid & 255;
    const u32* p0 = t ? oab : oba;
    const u32* p1 = t ? obb : oaa;
    float* sums = t ? sums_b : sums_a;
    const int tc = tid & 31, tr = tid >> 5;
    float s0[4] = {0,0,0,0}, s1[4] = {0,0,0,0};
    float q00[4] = {0,0,0,0}, q11[4] = {0,0,0,0}, q01[4] = {0,0,0,0};
    const int rend = min((bx + 1) * R, N);
    for (int row = bx * R + tr; row < rend; row += 8) {
      uint2 v0 = *(const uint2*)&p0[row * 64 + tc * 2];
      uint2 v1 = *(const uint2*)&p1[row * 64 + tc * 2];
      float r0[4] = {blo(v0.x), bhi(v0.x), blo(v0.y), bhi(v0.y)};
      float r1[4] = {blo(v1.x), bhi(v1.x), blo(v1.y), bhi(v1.y)};
#pragma unroll
      for (int j = 0; j < 4; ++j) {
        s0[j] += r0[j]; s1[j] += r1[j];
        q00[j] += r0[j] * r0[j]; q11[j] += r1[j] * r1[j];
        q01[j] += r0[j] * r1[j];
      }
    }
    float* sm = (float*)WTl;             // reuse LDS: 5 x 128 floats
    for (int i = tid; i < 640; i += 256) sm[i] = 0.f;
    __syncthreads();
#pragma unroll
    for (int j = 0; j < 4; ++j) {
      int f = tc * 4 + j;
      atomicAdd(&sm[f], s0[j]);
      atomicAdd(&sm[128 + f], s1[j]);
      atomicAdd(&sm[256 + f], q00[j]);
      atomicAdd(&sm[384 + f], q11[j]);
      atomicAdd(&sm[512 + f], q01[j]);
    }
    __syncthreads();
    for (int i = tid; i < 640; i += 256) atomicAdd(&sums[i], sm[i]);
    return;
  }

  // ---- sem_score ----
  const int sid = bid - 512;
  const int rel = sid & 3, bx = sid >> 2;
  const u32* op = (rel == 0) ? oba : (rel == 1) ? oaa : (rel == 2) ? oab : obb;
  const u16* o = (const u16*)op;

  // stage WkT -> LDS (aligned uint4, no conversion)
  const uint4* Wg = (const uint4*)WkT;
#pragma unroll
  for (int i = 0; i < 8; ++i) {
    int id = tid + 256 * i;
    uint4 v = Wg[id];
    int n = id >> 4, k8 = (id & 15) << 3;
    *(uint4*)&WTl[n * 136 + k8] = v;
  }
  __syncthreads();

  const int lane = tid & 63, wl = tid >> 6;
  const int col = lane & 15, g = lane >> 4;
  const int nb = bx * 64 + wl * 16;

  float bv[8], qv[8];
#pragma unroll
  for (int c = 0; c < 8; ++c) {
    bv[c] = bk[c * 16 + col];
    qv[c] = q[c * 16 + col];
  }

  const int arow = min(nb + col, N - 1);
  const u16* orow = o + (size_t)arow * 128;
  bf16x8 af[4];
#pragma unroll
  for (int t = 0; t < 4; ++t) af[t] = *(const bf16x8*)&orow[t * 32 + g * 8];

  f32x4 acc[8];
#pragma unroll
  for (int c = 0; c < 8; ++c) acc[c] = (f32x4){bv[c], bv[c], bv[c], bv[c]};

#pragma unroll
  for (int c = 0; c < 8; ++c) {
    const u16* wrow = &WTl[(c * 16 + col) * 136];
#pragma unroll
    for (int t = 0; t < 4; ++t) {
      bf16x8 bf = *(const bf16x8*)&wrow[t * 32 + g * 8];
      acc[c] = __builtin_amdgcn_mfma_f32_16x16x32_bf16(af[t], bf, acc[c], 0, 0, 0);
    }
  }

  float p = 0.f;
  const int rowbase = nb + g * 4;
#pragma unroll
  for (int c = 0; c < 8; ++c) {
#pragma unroll
    for (int i = 0; i < 4; ++i) {
      int node = rowbase + i;
      if (node < N) p += fast_tanh(acc[c][i]) * qv[c];
    }
  }
#pragma unroll
  for (int off = 32; off > 0; off >>= 1) p += __shfl_down(p, off);
  if (lane == 0) red[wl] = p;
  __syncthreads();
  if (tid == 0) atomicAdd(&scores[rel], red[0] + red[1] + red[2] + red[3]);
}

// ---------------------------------------------------------------------------
// bn_final: inline semantic softmax + moment combine + normalize + write.
// ---------------------------------------------------------------------------
__global__ __launch_bounds__(256) void bn_final_kernel(
    const u32* __restrict__ oba, const u32* __restrict__ oaa,
    const u32* __restrict__ oab, const u32* __restrict__ obb,
    const float* __restrict__ scores, const float* __restrict__ sums_a,
    const float* __restrict__ sums_b,
    const float* __restrict__ gamma, const float* __restrict__ beta,
    float* __restrict__ out, int N)
{
  const int t = blockIdx.y;
  const u32* o0 = t ? oab : oba;
  const u32* o1 = t ? obb : oaa;
  const float* sums = t ? sums_b : sums_a;
  float* op = out + (size_t)t * N * 128;

  const float invN = 1.f / (float)N;
  const float sc0 = scores[2 * t] * invN, sc1 = scores[2 * t + 1] * invN;
  const float m = fmaxf(sc0, sc1);
  const float e0 = expf(sc0 - m), e1 = expf(sc1 - m);
  const float einv = 1.f / (e0 + e1);
  const float a0 = e0 * einv, a1 = e1 * einv;

  __shared__ float scale[128], shift[128];
  if (threadIdx.x < 128) {
    int f = threadIdx.x;
    float S0 = sums[f], S1 = sums[128 + f];
    float Q00 = sums[256 + f], Q11 = sums[384 + f], Q01 = sums[512 + f];
    float mu = (a0 * S0 + a1 * S1) * invN;
    float msq = (a0 * a0 * Q00 + 2.f * a0 * a1 * Q01 + a1 * a1 * Q11) * invN;
    float var = fmaxf(msq - mu * mu, 0.f);
    float rs = rsqrtf(var + 1e-5f);
    float gm = gamma[f] * rs;
    scale[f] = gm;
    shift[f] = beta[f] - mu * gm;
  }
  __syncthreads();
  size_t total = (size_t)N * 128;
  for (size_t base = ((size_t)blockIdx.x * 256 + threadIdx.x) * 8; base < total;
       base += (size_t)gridDim.x * 2048) {
    int f0 = (int)(base & 127);
    uint4 p = *(const uint4*)&o0[base >> 1];
    uint4 q = *(const uint4*)&o1[base >> 1];
    float4 r0, r1;
    r0.x = (a0 * blo(p.x) + a1 * blo(q.x)) * scale[f0 + 0] + shift[f0 + 0];
    r0.y = (a0 * bhi(p.x) + a1 * bhi(q.x)) * scale[f0 + 1] + shift[f0 + 1];
    r0.z = (a0 * blo(p.y) + a1 * blo(q.y)) * scale[f0 + 2] + shift[f0 + 2];
    r0.w = (a0 * bhi(p.y) + a1 * bhi(q.y)) * scale[f0 + 3] + shift[f0 + 3];
    r1.x = (a0 * blo(p.z) + a1 * blo(q.z)) * scale[f0 + 4] + shift[f0 + 4];
    r1.y = (a0 * bhi(p.z) + a1 * bhi(q.z)) * scale[f0 + 5] + shift[f0 + 5];
    r1.z = (a0 * blo(p.w) + a1 * blo(q.w)) * scale[f0 + 6] + shift[f0 + 6];
    r1.w = (a0 * bhi(p.w) + a1 * bhi(q.w)) * scale[f0 + 7] + shift[f0 + 7];
    *(float4*)&op[base] = r0;
    *(float4*)&op[base + 4] = r1;
  }
}

extern "C" void kernel_launch(void* const* d_in, const int* in_sizes, int n_in,
                              void* d_out, int out_size, void* d_ws, size_t ws_size,
                              hipStream_t stream)
{
  const float* x_a      = (const float*)d_in[0];
  const float* x_b      = (const float*)d_in[1];
  const int* ei_ab      = (const int*)d_in[2];
  const int* ei_ba      = (const int*)d_in[3];
  const int* ei_aa      = (const int*)d_in[4];
  const int* ei_bb      = (const int*)d_in[5];
  const float* W_a      = (const float*)d_in[6];
  const float* b_a      = (const float*)d_in[7];
  const float* W_b      = (const float*)d_in[8];
  const float* b_b      = (const float*)d_in[9];
  const float* att_ab_s = (const float*)d_in[10];
  const float* att_ab_d = (const float*)d_in[11];
  const float* att_ba_s = (const float*)d_in[12];
  const float* att_ba_d = (const float*)d_in[13];
  const float* att_aa_s = (const float*)d_in[14];
  const float* att_aa_d = (const float*)d_in[15];
  const float* att_bb_s = (const float*)d_in[16];
  const float* att_bb_d = (const float*)d_in[17];
  const float* Wk       = (const float*)d_in[18];
  const float* bk       = (const float*)d_in[19];
  const float* q        = (const float*)d_in[20];
  const float* gamma    = (const float*)d_in[21];
  const float* beta     = (const float*)d_in[22];

  const int N = in_sizes[0] / 128;
  const int E = in_sizes[2] / 2;

  char* wp = (char*)d_ws;
  auto alloc = [&](size_t bytes) -> void* {
    void* p = (void*)wp;
    wp += (bytes + 255) & ~(size_t)255;
    return p;
  };
  u16* h_a = (u16*)alloc((size_t)N * 128 * 2);
  u16* h_b = (u16*)alloc((size_t)N * 128 * 2);
  float* A[8];
  for (int i = 0; i < 8; ++i) A[i] = (float*)alloc((size_t)N * 8 * 4);
  int* off    = (int*)alloc((size_t)4 * N * 4);
  int* cursor = (int*)alloc((size_t)4 * N * 4);
  int* bsum   = (int*)alloc(1024);
  int* ssrc   = (int*)alloc((size_t)4 * E * 4);
  u32* o_ab = (u32*)alloc((size_t)N * 64 * 4);   // packed relu bf16
  u32* o_ba = (u32*)alloc((size_t)N * 64 * 4);
  u32* o_aa = (u32*)alloc((size_t)N * 64 * 4);
  u32* o_bb = (u32*)alloc((size_t)N * 64 * 4);
  float* scores = (float*)alloc(16);             // 256B slot
  float* sums_a = (float*)alloc(2560);           // 5 x 128 f32
  float* sums_b = (float*)alloc(2560);
  u16* WT_a = (u16*)alloc(128 * 128 * 2);
  u16* WT_b = (u16*)alloc(128 * 128 * 2);
  u16* WT_k = (u16*)alloc(128 * 128 * 2);
  if ((size_t)(wp - (char*)d_ws) > ws_size) return;

  hipMemsetAsync(off, 0, (size_t)4 * N * 4, stream);
  hipMemsetAsync(scores, 0, 5376, stream);       // scores+sums_a+sums_b contiguous

  // --- weight prep (W_a, W_b, Wk -> transposed bf16) ---
  dim3 gw(64, 3);
  wprep_kernel<<<gw, 256, 0, stream>>>(W_a, W_b, Wk, WT_a, WT_b, WT_k);

  // --- K1: proj (both types) | hist (4 rel) ---
  // relation order: 0=ab 1=ba 2=aa 3=bb
  // type a att slots: ab_s, aa_s, aa_d, ba_d -> A[0..3]
  // type b att slots: ab_d, bb_s, bb_d, ba_s -> A[4..7]
  const int gproj = (N + 63) / 64;
  const int gE = (E + 255) / 256;
  const int interleave = (gE == gproj) ? 1 : 0;
  const int g1total = 2 * gproj + 4 * gE;
  fused1_kernel<<<g1total, 256, 0, stream>>>(
      x_a, x_b, WT_a, WT_b, b_a, b_b,
      att_ab_s, att_aa_s, att_aa_d, att_ba_d,
      att_ab_d, att_bb_s, att_bb_d, att_ba_s,
      h_a, h_b,
      A[0], A[1], A[2], A[3], A[4], A[5], A[6], A[7],
      ei_ab, ei_ba, ei_aa, ei_bb,
      off, N, E, gproj, gE, interleave);

  // --- CSR scans + scatter (scan2 folded into scan3) ---
  const int M = 4 * N;
  const int G1 = (M + 2047) / 2048;          // <= 256 for N <= 131072
  scan1_kernel<<<G1, 256, 0, stream>>>(off, M, bsum);
  scan3_kernel<<<G1, 256, 0, stream>>>(off, bsum, M, cursor);
  dim3 gsc(gE, 4);
  scatter_kernel<<<gsc, 256, 0, stream>>>(ei_ab, ei_ba, ei_aa, ei_bb, E, N, cursor, ssrc);

  // --- fused softmax + aggregate ---
  dim3 gag((N + 3) / 4, 4);
  aggregate_kernel<<<gag, 256, 0, stream>>>(
      off, ssrc,
      A[0], A[7], A[1], A[5],          // aS per relation: ab,ba,aa,bb
      A[4], A[3], A[2], A[6],          // aD per relation
      h_a, h_b, h_a, h_b,
      o_ab, o_ba, o_aa, o_bb, N, E);

  // --- K2: bn 5-moment stats | semantic scores (slot order ba,aa,ab,bb) ---
  const int R = (N + 255) / 256;
  const int g2total = 512 + 4 * gproj;
  fused2_kernel<<<g2total, 256, 0, stream>>>(
      o_ba, o_aa, o_ab, o_bb, WT_k, bk, q, scores, sums_a, sums_b, N, R, gproj);

  // --- bn_final with inline softmax + moment combine ---
  float* out = (float*)d_out;
  dim3 gbf(1024, 2);
  bn_final_kernel<<<gbf, 256, 0, stream>>>(o_ba, o_aa, o_ab, o_bb, scores,
                                           sums_a, sums_b, gamma, beta, out, N);
}

// Round 12
// 633.398 us; speedup vs baseline: 1.1112x; 1.0031x over previous
//
#include <hip/hip_runtime.h>

using u16 = unsigned short;
using u32 = unsigned int;
using bf16x8 = __attribute__((ext_vector_type(8))) short;
using f32x4  = __attribute__((ext_vector_type(4))) float;

__device__ __forceinline__ float bf2f(u16 v) { return __uint_as_float(((u32)v) << 16); }
__device__ __forceinline__ float blo(u32 u) { return __uint_as_float(u << 16); }
__device__ __forceinline__ float bhi(u32 u) { return __uint_as_float(u & 0xffff0000u); }
__device__ __forceinline__ u16 f2bf(float f) {
  u32 u = __float_as_uint(f);
  u += 0x7fffu + ((u >> 16) & 1u);   // RNE
  return (u16)(u >> 16);
}
__device__ __forceinline__ float fast_tanh(float x) {
  float cx = fminf(fmaxf(x, -9.f), 9.f);
  float e = __expf(2.f * cx);
  return (e - 1.f) / (e + 1.f);
}

// ---------------------------------------------------------------------------
// Prep: (a) W f32 [k][n] -> WT bf16 [n][k] for W_a/W_b/Wk; (b) zero off (cnt);
// (c) zero scores+sums span. Replaces wprep + 2 hipMemsetAsync (-2 launches).
// ---------------------------------------------------------------------------
__global__ __launch_bounds__(256) void prep_kernel(
    const float* __restrict__ Wa, const float* __restrict__ Wb,
    const float* __restrict__ Wk,
    u16* __restrict__ Ta, u16* __restrict__ Tb, u16* __restrict__ Tk,
    int* __restrict__ off, int M, float* __restrict__ zf, int ZF)
{
  const int bid = blockIdx.x, tid = threadIdx.x;
  if (bid < 192) {                       // weight transpose-convert
    int w = bid >> 6, part = bid & 63;
    const float* W = (w == 0) ? Wa : (w == 1) ? Wb : Wk;
    u16* T = (w == 0) ? Ta : (w == 1) ? Tb : Tk;
    int idx = part * 256 + tid;
    int k = idx >> 7, n = idx & 127;
    T[n * 128 + k] = f2bf(W[idx]);
    return;
  }
  int zb = bid - 192;
  int Z = (M + 2047) / 2048;
  if (zb < Z) {                          // zero cnt/off
    int base = zb * 2048 + tid * 8;
#pragma unroll
    for (int j = 0; j < 8; ++j)
      if (base + j < M) off[base + j] = 0;
    return;
  }
  for (int i = tid; i < ZF; i += 256) zf[i] = 0.f;   // zero scores+sums
}

// ---------------------------------------------------------------------------
// K1: fused {proj (both types, WT uint4-staged in LDS) | hist (4 rel)}.
// Hist: 4 edges/thread, independent fire-and-forget atomics (ILP instead of
// occupancy — proj's LDS caps blocks/CU). Interleave [proj,proj,hist].
// proj: D = WT-frag (A) x x-frag (B) = h^T tile; lane (col,g) holds feats
// c*16+4g+{0..3} of node nb+col; x split hi/lo bf16 (trunc hi + RNE lo,
// combined err <= 2^-17 |x| — bf16 h-storage error dominates).
// ---------------------------------------------------------------------------
__global__ __launch_bounds__(256) void fused1_kernel(
    const float* __restrict__ x_a, const float* __restrict__ x_b,
    const u16* __restrict__ WTa, const u16* __restrict__ WTb,
    const float* __restrict__ b_a, const float* __restrict__ b_b,
    const float* __restrict__ at0a, const float* __restrict__ at1a,
    const float* __restrict__ at2a, const float* __restrict__ at3a,
    const float* __restrict__ at0b, const float* __restrict__ at1b,
    const float* __restrict__ at2b, const float* __restrict__ at3b,
    u16* __restrict__ ha, u16* __restrict__ hb,
    float* __restrict__ a0a, float* __restrict__ a1a,
    float* __restrict__ a2a, float* __restrict__ a3a,
    float* __restrict__ a0b, float* __restrict__ a1b,
    float* __restrict__ a2b, float* __restrict__ a3b,
    const int* __restrict__ e0, const int* __restrict__ e1,
    const int* __restrict__ e2, const int* __restrict__ e3,
    int* __restrict__ cnt,
    int N, int E, int gproj, int nH)
{
  __shared__ __align__(16) u16 WTl[128 * 136];
  const int tid = threadIdx.x;
  const int bid = blockIdx.x;
  const int nP = 2 * gproj;
  const int tri = min(nP >> 1, nH);

  int role, idx;
  if (bid < 3 * tri) {
    int slot = bid % 3, grp = bid / 3;
    if (slot < 2) { role = 0; idx = grp * 2 + slot; }
    else          { role = 1; idx = grp; }
  } else {
    int rem = bid - 3 * tri;
    int pLeft = nP - 2 * tri;
    if (rem < pLeft) { role = 0; idx = 2 * tri + rem; }
    else             { role = 1; idx = tri + (rem - pLeft); }
  }

  if (role == 1) {                 // ---- hist: 4 independent atomics ----
    const int r = idx & 3, ex = idx >> 2;
    const int* ei = (r == 0) ? e0 : (r == 1) ? e1 : (r == 2) ? e2 : e3;
    const int base = ex * 1024 + tid;
    int d[4];
#pragma unroll
    for (int j = 0; j < 4; ++j) {
      int e = base + j * 256;
      d[j] = (e < E) ? ei[E + e] : -1;
    }
#pragma unroll
    for (int j = 0; j < 4; ++j)
      if (d[j] >= 0) atomicAdd(&cnt[r * N + d[j]], 1);
    return;
  }

  // ---- proj ----
  const int ty = idx >= gproj;
  const int bx = idx - (ty ? gproj : 0);
  const float* x    = ty ? x_b : x_a;
  const u16*  WT    = ty ? WTb : WTa;
  const float* bias = ty ? b_b : b_a;
  const float* att0 = ty ? at0b : at0a;
  const float* att1 = ty ? at1b : at1a;
  const float* att2 = ty ? at2b : at2a;
  const float* att3 = ty ? at3b : at3a;
  u16* h_out = ty ? hb : ha;
  float* al0 = ty ? a0b : a0a;
  float* al1 = ty ? a1b : a1a;
  float* al2 = ty ? a2b : a2a;
  float* al3 = ty ? a3b : a3a;

  // stage WT -> LDS with aligned uint4 copies (no conversion, conflict-free)
  const uint4* Wg = (const uint4*)WT;          // 2048 x 16B
#pragma unroll
  for (int i = 0; i < 8; ++i) {
    int id = tid + 256 * i;                    // n = id>>4, k8 = (id&15)*8
    uint4 v = Wg[id];
    int n = id >> 4, k8 = (id & 15) << 3;
    *(uint4*)&WTl[n * 136 + k8] = v;
  }
  __syncthreads();

  const int lane = tid & 63, wl = tid >> 6;
  const int col = lane & 15, g = lane >> 4;
  const int nb = bx * 64 + wl * 16;
  const int node = nb + col;
  const bool ok = node < N;

  const int arow = min(node, N - 1);
  const float* xr = x + (size_t)arow * 128;
  bf16x8 xh[4], xlo[4];
#pragma unroll
  for (int t = 0; t < 4; ++t) {
    float4 u = *(const float4*)&xr[t * 32 + g * 8];
    float4 v = *(const float4*)&xr[t * 32 + g * 8 + 4];
    float e[8] = {u.x, u.y, u.z, u.w, v.x, v.y, v.z, v.w};
    bf16x8 h8, l8;
#pragma unroll
    for (int j = 0; j < 8; ++j) {
      u16 hbt = (u16)(__float_as_uint(e[j]) >> 16);   // trunc split (cheap)
      h8[j] = (short)hbt;
      l8[j] = (short)f2bf(e[j] - bf2f(hbt));
    }
    xh[t] = h8; xlo[t] = l8;
  }

  f32x4 acc[8];
#pragma unroll
  for (int c = 0; c < 8; ++c) {
    float4 bv = *(const float4*)&bias[c * 16 + g * 4];
    acc[c] = (f32x4){bv.x, bv.y, bv.z, bv.w};
  }

#pragma unroll
  for (int c = 0; c < 8; ++c) {
    const u16* wrow = &WTl[(c * 16 + col) * 136];
#pragma unroll
    for (int t = 0; t < 4; ++t) {
      bf16x8 wf = *(const bf16x8*)&wrow[t * 32 + g * 8];
      acc[c] = __builtin_amdgcn_mfma_f32_16x16x32_bf16(wf, xh[t],  acc[c], 0, 0, 0);
      acc[c] = __builtin_amdgcn_mfma_f32_16x16x32_bf16(wf, xlo[t], acc[c], 0, 0, 0);
    }
  }

  if (ok) {
#pragma unroll
    for (int c = 0; c < 8; ++c) {
      uint2 hv;
      hv.x = (u32)f2bf(acc[c][0]) | ((u32)f2bf(acc[c][1]) << 16);
      hv.y = (u32)f2bf(acc[c][2]) | ((u32)f2bf(acc[c][3]) << 16);
      *(uint2*)(h_out + (size_t)node * 128 + c * 16 + g * 4) = hv;
    }
  }

#pragma unroll
  for (int c = 0; c < 8; ++c) {
    float4 a0v = *(const float4*)&att0[c * 16 + g * 4];
    float4 a1v = *(const float4*)&att1[c * 16 + g * 4];
    float4 a2v = *(const float4*)&att2[c * 16 + g * 4];
    float4 a3v = *(const float4*)&att3[c * 16 + g * 4];
    float p0 = acc[c][0] * a0v.x + acc[c][1] * a0v.y + acc[c][2] * a0v.z + acc[c][3] * a0v.w;
    float p1 = acc[c][0] * a1v.x + acc[c][1] * a1v.y + acc[c][2] * a1v.z + acc[c][3] * a1v.w;
    float p2 = acc[c][0] * a2v.x + acc[c][1] * a2v.y + acc[c][2] * a2v.z + acc[c][3] * a2v.w;
    float p3 = acc[c][0] * a3v.x + acc[c][1] * a3v.y + acc[c][2] * a3v.z + acc[c][3] * a3v.w;
    p0 += __shfl_xor(p0, 16); p0 += __shfl_xor(p0, 32);
    p1 += __shfl_xor(p1, 16); p1 += __shfl_xor(p1, 32);
    p2 += __shfl_xor(p2, 16); p2 += __shfl_xor(p2, 32);
    p3 += __shfl_xor(p3, 16); p3 += __shfl_xor(p3, 32);
    if (ok && g == 0) {
      al0[node * 8 + c] = p0;
      al1[node * 8 + c] = p1;
      al2[node * 8 + c] = p2;
      al3[node * 8 + c] = p3;
    }
  }
}

// ------------------------- CSR scans + scatter -----------------------------
__global__ __launch_bounds__(256) void scan1_kernel(int* __restrict__ data, int M,
                                                    int* __restrict__ bsum)
{
  __shared__ int ls[256];
  const int tid = threadIdx.x;
  const int base = blockIdx.x * 2048 + tid * 8;
  int v[8]; int s = 0;
#pragma unroll
  for (int j = 0; j < 8; ++j) v[j] = (base + j < M) ? data[base + j] : 0;
#pragma unroll
  for (int j = 0; j < 8; ++j) { int t = v[j]; v[j] = s; s += t; }
  ls[tid] = s;
  __syncthreads();
  for (int off = 1; off < 256; off <<= 1) {
    int t = (tid >= off) ? ls[tid - off] : 0;
    __syncthreads();
    ls[tid] += t;
    __syncthreads();
  }
  int texcl = ls[tid] - s;
#pragma unroll
  for (int j = 0; j < 8; ++j)
    if (base + j < M) data[base + j] = v[j] + texcl;
  if (tid == 255) bsum[blockIdx.x] = ls[255];
}

// scan3: block computes its own prefix over bsum (G1 <= 256), adds, mirrors.
__global__ __launch_bounds__(256) void scan3_kernel(int* __restrict__ data,
                                                    const int* __restrict__ bsum, int M,
                                                    int* __restrict__ cursor)
{
  __shared__ int rs[4];
  const int tid = threadIdx.x;
  int v = (tid < (int)blockIdx.x) ? bsum[tid] : 0;   // tid<bid<=G1-1 -> in range
#pragma unroll
  for (int off = 32; off > 0; off >>= 1) v += __shfl_down(v, off);
  if ((tid & 63) == 0) rs[tid >> 6] = v;
  __syncthreads();
  const int add = rs[0] + rs[1] + rs[2] + rs[3];
  const int base = blockIdx.x * 2048 + tid * 8;
#pragma unroll
  for (int j = 0; j < 8; ++j) {
    int i = base + j;
    if (i < M) { int t = data[i] + add; data[i] = t; cursor[i] = t; }
  }
}

__global__ __launch_bounds__(256) void scatter_kernel(
    const int* __restrict__ e0, const int* __restrict__ e1,
    const int* __restrict__ e2, const int* __restrict__ e3,
    int E, int N, int* __restrict__ cursor, int* __restrict__ ssrc)
{
  const int r = blockIdx.y;
  const int* ei = (r == 0) ? e0 : (r == 1) ? e1 : (r == 2) ? e2 : e3;
  int e = blockIdx.x * 256 + threadIdx.x;
  if (e >= E) return;
  int s = ei[e], d = ei[E + e];
  int p = atomicAdd(&cursor[r * N + d], 1);
  ssrc[p] = s;
}

// ---------------------------------------------------------------------------
// Fused segment-softmax + aggregate: 1 wave per dst node, 4-edge chunks.
// Weight dedup via shfl (R11). Output: relu(o) packed bf16.
// NOTE: VALU-insensitive (R11 A/B) — bound by gather memory throughput.
// ---------------------------------------------------------------------------
__global__ __launch_bounds__(256) void aggregate_kernel(
    const int* __restrict__ off, const int* __restrict__ ssrc,
    const float* __restrict__ aS0, const float* __restrict__ aS1,
    const float* __restrict__ aS2, const float* __restrict__ aS3,
    const float* __restrict__ aD0, const float* __restrict__ aD1,
    const float* __restrict__ aD2, const float* __restrict__ aD3,
    const u16* __restrict__ h0, const u16* __restrict__ h1,
    const u16* __restrict__ h2, const u16* __restrict__ h3,
    u32* __restrict__ o0, u32* __restrict__ o1,
    u32* __restrict__ o2, u32* __restrict__ o3,
    int N, int E)
{
  const int r = blockIdx.y;
  const float* aS = (r == 0) ? aS0 : (r == 1) ? aS1 : (r == 2) ? aS2 : aS3;
  const float* aD = (r == 0) ? aD0 : (r == 1) ? aD1 : (r == 2) ? aD2 : aD3;
  const u16*   h  = (r == 0) ? h0  : (r == 1) ? h1  : (r == 2) ? h2  : h3;
  u32*         o  = (r == 0) ? o0  : (r == 1) ? o1  : (r == 2) ? o2  : o3;

  const int wave = threadIdx.x >> 6, lane = threadIdx.x & 63;
  const int n = blockIdx.x * 4 + wave;
  if (n >= N) return;
  const int head = lane >> 3;
  const int hw = (lane >> 2) & 7;
  const int ew = lane & 3;
  const int srcb = head * 4;
  const int idx = r * N + n;
  const int p0 = off[idx];
  const int p1 = (idx + 1 < 4 * N) ? off[idx + 1] : 4 * E;
  const float aDw = aD[n * 8 + hw];
  const u32* h32 = (const u32*)h;

  float acc0 = 0.f, acc1 = 0.f, den = 0.f;
  int p = p0;
  for (; p + 4 <= p1; p += 4) {
    const int s0 = ssrc[p], s1 = ssrc[p + 1], s2 = ssrc[p + 2], s3 = ssrc[p + 3];
    const int sw = (ew & 1) ? ((ew & 2) ? s3 : s1) : ((ew & 2) ? s2 : s0);
    float lw = aS[sw * 8 + hw] + aDw;
    lw = fmaxf(lw, 0.2f * lw);
    const float wme = __expf(lw);
    const float w0 = __shfl(wme, srcb + 0);
    const float w1 = __shfl(wme, srcb + 1);
    const float w2 = __shfl(wme, srcb + 2);
    const float w3 = __shfl(wme, srcb + 3);
    const u32 v0 = h32[s0 * 64 + lane];
    const u32 v1 = h32[s1 * 64 + lane];
    const u32 v2 = h32[s2 * 64 + lane];
    const u32 v3 = h32[s3 * 64 + lane];
    den += (w0 + w1) + (w2 + w3);
    acc0 += w0 * blo(v0) + w1 * blo(v1) + w2 * blo(v2) + w3 * blo(v3);
    acc1 += w0 * bhi(v0) + w1 * bhi(v1) + w2 * bhi(v2) + w3 * bhi(v3);
  }
  const int rem = p1 - p;
  if (rem > 0) {
    const int s0 = ssrc[p];
    const int s1 = ssrc[(rem > 1) ? p + 1 : p];
    const int s2 = ssrc[(rem > 2) ? p + 2 : p];
    const int swi = (ew < rem) ? ew : 0;
    const int sw = (swi == 0) ? s0 : (swi == 1) ? s1 : s2;
    float lw = aS[sw * 8 + hw] + aDw;
    lw = fmaxf(lw, 0.2f * lw);
    const float wme = __expf(lw);
    const float w0 = __shfl(wme, srcb + 0);
    float w1 = __shfl(wme, srcb + 1);
    float w2 = __shfl(wme, srcb + 2);
    w1 = (rem > 1) ? w1 : 0.f;
    w2 = (rem > 2) ? w2 : 0.f;
    const u32 v0 = h32[s0 * 64 + lane];
    const u32 v1 = h32[s1 * 64 + lane];
    const u32 v2 = h32[s2 * 64 + lane];
    den += w0 + w1 + w2;
    acc0 += w0 * blo(v0) + w1 * blo(v1) + w2 * blo(v2);
    acc1 += w0 * bhi(v0) + w1 * bhi(v1) + w2 * bhi(v2);
  }
  const float inv = 1.f / (den + 1e-16f);
  const float r0 = fmaxf(acc0 * inv, 0.f);
  const float r1 = fmaxf(acc1 * inv, 0.f);
  o[n * 64 + lane] = (u32)f2bf(r0) | ((u32)f2bf(r1) << 16);
}

// ---------------------------------------------------------------------------
// K2: fused {bn 5-moment stats (attn-independent) | MFMA semantic score}.
// sem stages WkT into LDS via uint4; stats blocks reuse the LDS as scratch.
// ---------------------------------------------------------------------------
__global__ __launch_bounds__(256) void fused2_kernel(
    const u32* __restrict__ oba, const u32* __restrict__ oaa,
    const u32* __restrict__ oab, const u32* __restrict__ obb,
    const u16* __restrict__ WkT, const float* __restrict__ bk,
    const float* __restrict__ q, float* __restrict__ scores,
    float* __restrict__ sums_a, float* __restrict__ sums_b,
    int N, int R, int gproj)
{
  __shared__ __align__(16) u16 WTl[128 * 136];
  __shared__ float red[4];
  const int tid = threadIdx.x;
  const int bid = blockIdx.x;

  if (bid < 512) {                       // ---- bn 5-moment stats ----
    const int t = bid >> 8, bx = bid & 255;
    const u32* p0 = t ? oab : oba;
    const u32* p1 = t ? obb : oaa;
    float* sums = t ? sums_b : sums_a;
    const int tc = tid & 31, tr = tid >> 5;
    float s0[4] = {0,0,0,0}, s1[4] = {0,0,0,0};
    float q00[4] = {0,0,0,0}, q11[4] = {0,0,0,0}, q01[4] = {0,0,0,0};
    const int rend = min((bx + 1) * R, N);
    for (int row = bx * R + tr; row < rend; row += 8) {
      uint2 v0 = *(const uint2*)&p0[row * 64 + tc * 2];
      uint2 v1 = *(const uint2*)&p1[row * 64 + tc * 2];
      float r0[4] = {blo(v0.x), bhi(v0.x), blo(v0.y), bhi(v0.y)};
      float r1[4] = {blo(v1.x), bhi(v1.x), blo(v1.y), bhi(v1.y)};
#pragma unroll
      for (int j = 0; j < 4; ++j) {
        s0[j] += r0[j]; s1[j] += r1[j];
        q00[j] += r0[j] * r0[j]; q11[j] += r1[j] * r1[j];
        q01[j] += r0[j] * r1[j];
      }
    }
    float* sm = (float*)WTl;             // reuse LDS: 5 x 128 floats
    for (int i = tid; i < 640; i += 256) sm[i] = 0.f;
    __syncthreads();
#pragma unroll
    for (int j = 0; j < 4; ++j) {
      int f = tc * 4 + j;
      atomicAdd(&sm[f], s0[j]);
      atomicAdd(&sm[128 + f], s1[j]);
      atomicAdd(&sm[256 + f], q00[j]);
      atomicAdd(&sm[384 + f], q11[j]);
      atomicAdd(&sm[512 + f], q01[j]);
    }
    __syncthreads();
    for (int i = tid; i < 640; i += 256) atomicAdd(&sums[i], sm[i]);
    return;
  }

  // ---- sem_score ----
  const int sid = bid - 512;
  const int rel = sid & 3, bx = sid >> 2;
  const u32* op = (rel == 0) ? oba : (rel == 1) ? oaa : (rel == 2) ? oab : obb;
  const u16* o = (const u16*)op;

  // stage WkT -> LDS (aligned uint4, no conversion)
  const uint4* Wg = (const uint4*)WkT;
#pragma unroll
  for (int i = 0; i < 8; ++i) {
    int id = tid + 256 * i;
    uint4 v = Wg[id];
    int n = id >> 4, k8 = (id & 15) << 3;
    *(uint4*)&WTl[n * 136 + k8] = v;
  }
  __syncthreads();

  const int lane = tid & 63, wl = tid >> 6;
  const int col = lane & 15, g = lane >> 4;
  const int nb = bx * 64 + wl * 16;

  float bv[8], qv[8];
#pragma unroll
  for (int c = 0; c < 8; ++c) {
    bv[c] = bk[c * 16 + col];
    qv[c] = q[c * 16 + col];
  }

  const int arow = min(nb + col, N - 1);
  const u16* orow = o + (size_t)arow * 128;
  bf16x8 af[4];
#pragma unroll
  for (int t = 0; t < 4; ++t) af[t] = *(const bf16x8*)&orow[t * 32 + g * 8];

  f32x4 acc[8];
#pragma unroll
  for (int c = 0; c < 8; ++c) acc[c] = (f32x4){bv[c], bv[c], bv[c], bv[c]};

#pragma unroll
  for (int c = 0; c < 8; ++c) {
    const u16* wrow = &WTl[(c * 16 + col) * 136];
#pragma unroll
    for (int t = 0; t < 4; ++t) {
      bf16x8 bf = *(const bf16x8*)&wrow[t * 32 + g * 8];
      acc[c] = __builtin_amdgcn_mfma_f32_16x16x32_bf16(af[t], bf, acc[c], 0, 0, 0);
    }
  }

  float p = 0.f;
  const int rowbase = nb + g * 4;
#pragma unroll
  for (int c = 0; c < 8; ++c) {
#pragma unroll
    for (int i = 0; i < 4; ++i) {
      int node = rowbase + i;
      if (node < N) p += fast_tanh(acc[c][i]) * qv[c];
    }
  }
#pragma unroll
  for (int off = 32; off > 0; off >>= 1) p += __shfl_down(p, off);
  if (lane == 0) red[wl] = p;
  __syncthreads();
  if (tid == 0) atomicAdd(&scores[rel], red[0] + red[1] + red[2] + red[3]);
}

// ---------------------------------------------------------------------------
// bn_final: inline semantic softmax + moment combine + normalize + write.
// ---------------------------------------------------------------------------
__global__ __launch_bounds__(256) void bn_final_kernel(
    const u32* __restrict__ oba, const u32* __restrict__ oaa,
    const u32* __restrict__ oab, const u32* __restrict__ obb,
    const float* __restrict__ scores, const float* __restrict__ sums_a,
    const float* __restrict__ sums_b,
    const float* __restrict__ gamma, const float* __restrict__ beta,
    float* __restrict__ out, int N)
{
  const int t = blockIdx.y;
  const u32* o0 = t ? oab : oba;
  const u32* o1 = t ? obb : oaa;
  const float* sums = t ? sums_b : sums_a;
  float* op = out + (size_t)t * N * 128;

  const float invN = 1.f / (float)N;
  const float sc0 = scores[2 * t] * invN, sc1 = scores[2 * t + 1] * invN;
  const float m = fmaxf(sc0, sc1);
  const float e0 = expf(sc0 - m), e1 = expf(sc1 - m);
  const float einv = 1.f / (e0 + e1);
  const float a0 = e0 * einv, a1 = e1 * einv;

  __shared__ float scale[128], shift[128];
  if (threadIdx.x < 128) {
    int f = threadIdx.x;
    float S0 = sums[f], S1 = sums[128 + f];
    float Q00 = sums[256 + f], Q11 = sums[384 + f], Q01 = sums[512 + f];
    float mu = (a0 * S0 + a1 * S1) * invN;
    float msq = (a0 * a0 * Q00 + 2.f * a0 * a1 * Q01 + a1 * a1 * Q11) * invN;
    float var = fmaxf(msq - mu * mu, 0.f);
    float rs = rsqrtf(var + 1e-5f);
    float gm = gamma[f] * rs;
    scale[f] = gm;
    shift[f] = beta[f] - mu * gm;
  }
  __syncthreads();
  size_t total = (size_t)N * 128;
  for (size_t base = ((size_t)blockIdx.x * 256 + threadIdx.x) * 8; base < total;
       base += (size_t)gridDim.x * 2048) {
    int f0 = (int)(base & 127);
    uint4 p = *(const uint4*)&o0[base >> 1];
    uint4 q = *(const uint4*)&o1[base >> 1];
    float4 r0, r1;
    r0.x = (a0 * blo(p.x) + a1 * blo(q.x)) * scale[f0 + 0] + shift[f0 + 0];
    r0.y = (a0 * bhi(p.x) + a1 * bhi(q.x)) * scale[f0 + 1] + shift[f0 + 1];
    r0.z = (a0 * blo(p.y) + a1 * blo(q.y)) * scale[f0 + 2] + shift[f0 + 2];
    r0.w = (a0 * bhi(p.y) + a1 * bhi(q.y)) * scale[f0 + 3] + shift[f0 + 3];
    r1.x = (a0 * blo(p.z) + a1 * blo(q.z)) * scale[f0 + 4] + shift[f0 + 4];
    r1.y = (a0 * bhi(p.z) + a1 * bhi(q.z)) * scale[f0 + 5] + shift[f0 + 5];
    r1.z = (a0 * blo(p.w) + a1 * blo(q.w)) * scale[f0 + 6] + shift[f0 + 6];
    r1.w = (a0 * bhi(p.w) + a1 * bhi(q.w)) * scale[f0 + 7] + shift[f0 + 7];
    *(float4*)&op[base] = r0;
    *(float4*)&op[base + 4] = r1;
  }
}

extern "C" void kernel_launch(void* const* d_in, const int* in_sizes, int n_in,
                              void* d_out, int out_size, void* d_ws, size_t ws_size,
                              hipStream_t stream)
{
  const float* x_a      = (const float*)d_in[0];
  const float* x_b      = (const float*)d_in[1];
  const int* ei_ab      = (const int*)d_in[2];
  const int* ei_ba      = (const int*)d_in[3];
  const int* ei_aa      = (const int*)d_in[4];
  const int* ei_bb      = (const int*)d_in[5];
  const float* W_a      = (const float*)d_in[6];
  const float* b_a      = (const float*)d_in[7];
  const float* W_b      = (const float*)d_in[8];
  const float* b_b      = (const float*)d_in[9];
  const float* att_ab_s = (const float*)d_in[10];
  const float* att_ab_d = (const float*)d_in[11];
  const float* att_ba_s = (const float*)d_in[12];
  const float* att_ba_d = (const float*)d_in[13];
  const float* att_aa_s = (const float*)d_in[14];
  const float* att_aa_d = (const float*)d_in[15];
  const float* att_bb_s = (const float*)d_in[16];
  const float* att_bb_d = (const float*)d_in[17];
  const float* Wk       = (const float*)d_in[18];
  const float* bk       = (const float*)d_in[19];
  const float* q        = (const float*)d_in[20];
  const float* gamma    = (const float*)d_in[21];
  const float* beta     = (const float*)d_in[22];

  const int N = in_sizes[0] / 128;
  const int E = in_sizes[2] / 2;

  char* wp = (char*)d_ws;
  auto alloc = [&](size_t bytes) -> void* {
    void* p = (void*)wp;
    wp += (bytes + 255) & ~(size_t)255;
    return p;
  };
  u16* h_a = (u16*)alloc((size_t)N * 128 * 2);
  u16* h_b = (u16*)alloc((size_t)N * 128 * 2);
  float* A[8];
  for (int i = 0; i < 8; ++i) A[i] = (float*)alloc((size_t)N * 8 * 4);
  int* off    = (int*)alloc((size_t)4 * N * 4);
  int* cursor = (int*)alloc((size_t)4 * N * 4);
  int* bsum   = (int*)alloc(1024);
  int* ssrc   = (int*)alloc((size_t)4 * E * 4);
  u32* o_ab = (u32*)alloc((size_t)N * 64 * 4);   // packed relu bf16
  u32* o_ba = (u32*)alloc((size_t)N * 64 * 4);
  u32* o_aa = (u32*)alloc((size_t)N * 64 * 4);
  u32* o_bb = (u32*)alloc((size_t)N * 64 * 4);
  float* scores = (float*)alloc(16);             // 256B slot
  float* sums_a = (float*)alloc(2560);           // 5 x 128 f32
  float* sums_b = (float*)alloc(2560);
  u16* WT_a = (u16*)alloc(128 * 128 * 2);
  u16* WT_b = (u16*)alloc(128 * 128 * 2);
  u16* WT_k = (u16*)alloc(128 * 128 * 2);
  if ((size_t)(wp - (char*)d_ws) > ws_size) return;

  // --- prep: weight transpose-convert + zero off + zero scores/sums span ---
  const int M = 4 * N;
  const int Z = (M + 2047) / 2048;
  prep_kernel<<<192 + Z + 1, 256, 0, stream>>>(W_a, W_b, Wk, WT_a, WT_b, WT_k,
                                               off, M, scores, 1344);

  // --- K1: proj (both types) | hist (4 rel, 4 edges/thread) ---
  // relation order: 0=ab 1=ba 2=aa 3=bb
  // type a att slots: ab_s, aa_s, aa_d, ba_d -> A[0..3]
  // type b att slots: ab_d, bb_s, bb_d, ba_s -> A[4..7]
  const int gproj = (N + 63) / 64;
  const int gEh = (E + 1023) / 1024;
  const int nH = 4 * gEh;
  const int g1total = 2 * gproj + nH;
  fused1_kernel<<<g1total, 256, 0, stream>>>(
      x_a, x_b, WT_a, WT_b, b_a, b_b,
      att_ab_s, att_aa_s, att_aa_d, att_ba_d,
      att_ab_d, att_bb_s, att_bb_d, att_ba_s,
      h_a, h_b,
      A[0], A[1], A[2], A[3], A[4], A[5], A[6], A[7],
      ei_ab, ei_ba, ei_aa, ei_bb,
      off, N, E, gproj, nH);

  // --- CSR scans + scatter (scan2 folded into scan3) ---
  const int G1 = (M + 2047) / 2048;          // <= 256 for N <= 131072
  scan1_kernel<<<G1, 256, 0, stream>>>(off, M, bsum);
  scan3_kernel<<<G1, 256, 0, stream>>>(off, bsum, M, cursor);
  const int gE = (E + 255) / 256;
  dim3 gsc(gE, 4);
  scatter_kernel<<<gsc, 256, 0, stream>>>(ei_ab, ei_ba, ei_aa, ei_bb, E, N, cursor, ssrc);

  // --- fused softmax + aggregate ---
  dim3 gag((N + 3) / 4, 4);
  aggregate_kernel<<<gag, 256, 0, stream>>>(
      off, ssrc,
      A[0], A[7], A[1], A[5],          // aS per relation: ab,ba,aa,bb
      A[4], A[3], A[2], A[6],          // aD per relation
      h_a, h_b, h_a, h_b,
      o_ab, o_ba, o_aa, o_bb, N, E);

  // --- K2: bn 5-moment stats | semantic scores (slot order ba,aa,ab,bb) ---
  const int R = (N + 255) / 256;
  const int g2total = 512 + 4 * gproj;
  fused2_kernel<<<g2total, 256, 0, stream>>>(
      o_ba, o_aa, o_ab, o_bb, WT_k, bk, q, scores, sums_a, sums_b, N, R, gproj);

  // --- bn_final with inline softmax + moment combine ---
  float* out = (float*)d_out;
  dim3 gbf(1024, 2);
  bn_final_kernel<<<gbf, 256, 0, stream>>>(o_ba, o_aa, o_ab, o_bb, scores,
                                           sums_a, sums_b, gamma, beta, out, N);
}

// Round 13
// 625.755 us; speedup vs baseline: 1.1248x; 1.0122x over previous
//
#include <hip/hip_runtime.h>

using u16 = unsigned short;
using u32 = unsigned int;
using bf16x8 = __attribute__((ext_vector_type(8))) short;
using f32x4  = __attribute__((ext_vector_type(4))) float;

__device__ __forceinline__ float bf2f(u16 v) { return __uint_as_float(((u32)v) << 16); }
__device__ __forceinline__ float blo(u32 u) { return __uint_as_float(u << 16); }
__device__ __forceinline__ float bhi(u32 u) { return __uint_as_float(u & 0xffff0000u); }
__device__ __forceinline__ u16 f2bf(float f) {
  u32 u = __float_as_uint(f);
  u += 0x7fffu + ((u >> 16) & 1u);   // RNE
  return (u16)(u >> 16);
}
// fast tanh: exp + FAST division (__fdividef -> v_rcp+v_mul, ~1ulp).
// Score is a mean over N=100k nodes -> rcp rounding noise is negligible.
__device__ __forceinline__ float fast_tanh(float x) {
  float cx = fminf(fmaxf(x, -9.f), 9.f);
  float e = __expf(2.f * cx);
  return __fdividef(e - 1.f, e + 1.f);
}

// ---------------------------------------------------------------------------
// Prep: (a) W f32 [k][n] -> WT bf16 [n][k] for W_a/W_b/Wk; (b) zero off (cnt);
// (c) zero scores+sums span. Replaces wprep + 2 hipMemsetAsync (-2 launches).
// ---------------------------------------------------------------------------
__global__ __launch_bounds__(256) void prep_kernel(
    const float* __restrict__ Wa, const float* __restrict__ Wb,
    const float* __restrict__ Wk,
    u16* __restrict__ Ta, u16* __restrict__ Tb, u16* __restrict__ Tk,
    int* __restrict__ off, int M, float* __restrict__ zf, int ZF)
{
  const int bid = blockIdx.x, tid = threadIdx.x;
  if (bid < 192) {                       // weight transpose-convert
    int w = bid >> 6, part = bid & 63;
    const float* W = (w == 0) ? Wa : (w == 1) ? Wb : Wk;
    u16* T = (w == 0) ? Ta : (w == 1) ? Tb : Tk;
    int idx = part * 256 + tid;
    int k = idx >> 7, n = idx & 127;
    T[n * 128 + k] = f2bf(W[idx]);
    return;
  }
  int zb = bid - 192;
  int Z = (M + 2047) / 2048;
  if (zb < Z) {                          // zero cnt/off
    int base = zb * 2048 + tid * 8;
#pragma unroll
    for (int j = 0; j < 8; ++j)
      if (base + j < M) off[base + j] = 0;
    return;
  }
  for (int i = tid; i < ZF; i += 256) zf[i] = 0.f;   // zero scores+sums
}

// ---------------------------------------------------------------------------
// K1: fused {proj (both types, WT uint4-staged in LDS) | hist (4 rel)}.
// Hist: 4 edges/thread, independent fire-and-forget atomics (ILP instead of
// occupancy — proj's LDS caps blocks/CU). Interleave [proj,proj,hist].
// proj: D = WT-frag (A) x x-frag (B) = h^T tile; lane (col,g) holds feats
// c*16+4g+{0..3} of node nb+col; x split hi/lo bf16 (trunc hi + RNE lo).
// ---------------------------------------------------------------------------
__global__ __launch_bounds__(256) void fused1_kernel(
    const float* __restrict__ x_a, const float* __restrict__ x_b,
    const u16* __restrict__ WTa, const u16* __restrict__ WTb,
    const float* __restrict__ b_a, const float* __restrict__ b_b,
    const float* __restrict__ at0a, const float* __restrict__ at1a,
    const float* __restrict__ at2a, const float* __restrict__ at3a,
    const float* __restrict__ at0b, const float* __restrict__ at1b,
    const float* __restrict__ at2b, const float* __restrict__ at3b,
    u16* __restrict__ ha, u16* __restrict__ hb,
    float* __restrict__ a0a, float* __restrict__ a1a,
    float* __restrict__ a2a, float* __restrict__ a3a,
    float* __restrict__ a0b, float* __restrict__ a1b,
    float* __restrict__ a2b, float* __restrict__ a3b,
    const int* __restrict__ e0, const int* __restrict__ e1,
    const int* __restrict__ e2, const int* __restrict__ e3,
    int* __restrict__ cnt,
    int N, int E, int gproj, int nH)
{
  __shared__ __align__(16) u16 WTl[128 * 136];
  const int tid = threadIdx.x;
  const int bid = blockIdx.x;
  const int nP = 2 * gproj;
  const int tri = min(nP >> 1, nH);

  int role, idx;
  if (bid < 3 * tri) {
    int slot = bid % 3, grp = bid / 3;
    if (slot < 2) { role = 0; idx = grp * 2 + slot; }
    else          { role = 1; idx = grp; }
  } else {
    int rem = bid - 3 * tri;
    int pLeft = nP - 2 * tri;
    if (rem < pLeft) { role = 0; idx = 2 * tri + rem; }
    else             { role = 1; idx = tri + (rem - pLeft); }
  }

  if (role == 1) {                 // ---- hist: 4 independent atomics ----
    const int r = idx & 3, ex = idx >> 2;
    const int* ei = (r == 0) ? e0 : (r == 1) ? e1 : (r == 2) ? e2 : e3;
    const int base = ex * 1024 + tid;
    int d[4];
#pragma unroll
    for (int j = 0; j < 4; ++j) {
      int e = base + j * 256;
      d[j] = (e < E) ? ei[E + e] : -1;
    }
#pragma unroll
    for (int j = 0; j < 4; ++j)
      if (d[j] >= 0) atomicAdd(&cnt[r * N + d[j]], 1);
    return;
  }

  // ---- proj ----
  const int ty = idx >= gproj;
  const int bx = idx - (ty ? gproj : 0);
  const float* x    = ty ? x_b : x_a;
  const u16*  WT    = ty ? WTb : WTa;
  const float* bias = ty ? b_b : b_a;
  const float* att0 = ty ? at0b : at0a;
  const float* att1 = ty ? at1b : at1a;
  const float* att2 = ty ? at2b : at2a;
  const float* att3 = ty ? at3b : at3a;
  u16* h_out = ty ? hb : ha;
  float* al0 = ty ? a0b : a0a;
  float* al1 = ty ? a1b : a1a;
  float* al2 = ty ? a2b : a2a;
  float* al3 = ty ? a3b : a3a;

  // stage WT -> LDS with aligned uint4 copies (no conversion, conflict-free)
  const uint4* Wg = (const uint4*)WT;          // 2048 x 16B
#pragma unroll
  for (int i = 0; i < 8; ++i) {
    int id = tid + 256 * i;                    // n = id>>4, k8 = (id&15)*8
    uint4 v = Wg[id];
    int n = id >> 4, k8 = (id & 15) << 3;
    *(uint4*)&WTl[n * 136 + k8] = v;
  }
  __syncthreads();

  const int lane = tid & 63, wl = tid >> 6;
  const int col = lane & 15, g = lane >> 4;
  const int nb = bx * 64 + wl * 16;
  const int node = nb + col;
  const bool ok = node < N;

  const int arow = min(node, N - 1);
  const float* xr = x + (size_t)arow * 128;
  bf16x8 xh[4], xlo[4];
#pragma unroll
  for (int t = 0; t < 4; ++t) {
    float4 u = *(const float4*)&xr[t * 32 + g * 8];
    float4 v = *(const float4*)&xr[t * 32 + g * 8 + 4];
    float e[8] = {u.x, u.y, u.z, u.w, v.x, v.y, v.z, v.w};
    bf16x8 h8, l8;
#pragma unroll
    for (int j = 0; j < 8; ++j) {
      u16 hbt = (u16)(__float_as_uint(e[j]) >> 16);   // trunc split (cheap)
      h8[j] = (short)hbt;
      l8[j] = (short)f2bf(e[j] - bf2f(hbt));
    }
    xh[t] = h8; xlo[t] = l8;
  }

  f32x4 acc[8];
#pragma unroll
  for (int c = 0; c < 8; ++c) {
    float4 bv = *(const float4*)&bias[c * 16 + g * 4];
    acc[c] = (f32x4){bv.x, bv.y, bv.z, bv.w};
  }

#pragma unroll
  for (int c = 0; c < 8; ++c) {
    const u16* wrow = &WTl[(c * 16 + col) * 136];
#pragma unroll
    for (int t = 0; t < 4; ++t) {
      bf16x8 wf = *(const bf16x8*)&wrow[t * 32 + g * 8];
      acc[c] = __builtin_amdgcn_mfma_f32_16x16x32_bf16(wf, xh[t],  acc[c], 0, 0, 0);
      acc[c] = __builtin_amdgcn_mfma_f32_16x16x32_bf16(wf, xlo[t], acc[c], 0, 0, 0);
    }
  }

  if (ok) {
#pragma unroll
    for (int c = 0; c < 8; ++c) {
      uint2 hv;
      hv.x = (u32)f2bf(acc[c][0]) | ((u32)f2bf(acc[c][1]) << 16);
      hv.y = (u32)f2bf(acc[c][2]) | ((u32)f2bf(acc[c][3]) << 16);
      *(uint2*)(h_out + (size_t)node * 128 + c * 16 + g * 4) = hv;
    }
  }

#pragma unroll
  for (int c = 0; c < 8; ++c) {
    float4 a0v = *(const float4*)&att0[c * 16 + g * 4];
    float4 a1v = *(const float4*)&att1[c * 16 + g * 4];
    float4 a2v = *(const float4*)&att2[c * 16 + g * 4];
    float4 a3v = *(const float4*)&att3[c * 16 + g * 4];
    float p0 = acc[c][0] * a0v.x + acc[c][1] * a0v.y + acc[c][2] * a0v.z + acc[c][3] * a0v.w;
    float p1 = acc[c][0] * a1v.x + acc[c][1] * a1v.y + acc[c][2] * a1v.z + acc[c][3] * a1v.w;
    float p2 = acc[c][0] * a2v.x + acc[c][1] * a2v.y + acc[c][2] * a2v.z + acc[c][3] * a2v.w;
    float p3 = acc[c][0] * a3v.x + acc[c][1] * a3v.y + acc[c][2] * a3v.z + acc[c][3] * a3v.w;
    p0 += __shfl_xor(p0, 16); p0 += __shfl_xor(p0, 32);
    p1 += __shfl_xor(p1, 16); p1 += __shfl_xor(p1, 32);
    p2 += __shfl_xor(p2, 16); p2 += __shfl_xor(p2, 32);
    p3 += __shfl_xor(p3, 16); p3 += __shfl_xor(p3, 32);
    if (ok && g == 0) {
      al0[node * 8 + c] = p0;
      al1[node * 8 + c] = p1;
      al2[node * 8 + c] = p2;
      al3[node * 8 + c] = p3;
    }
  }
}

// ------------------------- CSR scans + scatter -----------------------------
__global__ __launch_bounds__(256) void scan1_kernel(int* __restrict__ data, int M,
                                                    int* __restrict__ bsum)
{
  __shared__ int ls[256];
  const int tid = threadIdx.x;
  const int base = blockIdx.x * 2048 + tid * 8;
  int v[8]; int s = 0;
#pragma unroll
  for (int j = 0; j < 8; ++j) v[j] = (base + j < M) ? data[base + j] : 0;
#pragma unroll
  for (int j = 0; j < 8; ++j) { int t = v[j]; v[j] = s; s += t; }
  ls[tid] = s;
  __syncthreads();
  for (int off = 1; off < 256; off <<= 1) {
    int t = (tid >= off) ? ls[tid - off] : 0;
    __syncthreads();
    ls[tid] += t;
    __syncthreads();
  }
  int texcl = ls[tid] - s;
#pragma unroll
  for (int j = 0; j < 8; ++j)
    if (base + j < M) data[base + j] = v[j] + texcl;
  if (tid == 255) bsum[blockIdx.x] = ls[255];
}

// scan3: block computes its own prefix over bsum (G1 <= 256), adds, mirrors.
__global__ __launch_bounds__(256) void scan3_kernel(int* __restrict__ data,
                                                    const int* __restrict__ bsum, int M,
                                                    int* __restrict__ cursor)
{
  __shared__ int rs[4];
  const int tid = threadIdx.x;
  int v = (tid < (int)blockIdx.x) ? bsum[tid] : 0;   // tid<bid<=G1-1 -> in range
#pragma unroll
  for (int off = 32; off > 0; off >>= 1) v += __shfl_down(v, off);
  if ((tid & 63) == 0) rs[tid >> 6] = v;
  __syncthreads();
  const int add = rs[0] + rs[1] + rs[2] + rs[3];
  const int base = blockIdx.x * 2048 + tid * 8;
#pragma unroll
  for (int j = 0; j < 8; ++j) {
    int i = base + j;
    if (i < M) { int t = data[i] + add; data[i] = t; cursor[i] = t; }
  }
}

__global__ __launch_bounds__(256) void scatter_kernel(
    const int* __restrict__ e0, const int* __restrict__ e1,
    const int* __restrict__ e2, const int* __restrict__ e3,
    int E, int N, int* __restrict__ cursor, int* __restrict__ ssrc)
{
  const int r = blockIdx.y;
  const int* ei = (r == 0) ? e0 : (r == 1) ? e1 : (r == 2) ? e2 : e3;
  int e = blockIdx.x * 256 + threadIdx.x;
  if (e >= E) return;
  int s = ei[e], d = ei[E + e];
  int p = atomicAdd(&cursor[r * N + d], 1);
  ssrc[p] = s;
}

// ---------------------------------------------------------------------------
// Fused segment-softmax + aggregate: 1 wave per dst node, 4-edge chunks.
// Weight dedup via shfl (R11). Output: relu(o) packed bf16.
// NOTE: VALU-insensitive (R11 A/B) — bound by gather memory throughput.
// ---------------------------------------------------------------------------
__global__ __launch_bounds__(256) void aggregate_kernel(
    const int* __restrict__ off, const int* __restrict__ ssrc,
    const float* __restrict__ aS0, const float* __restrict__ aS1,
    const float* __restrict__ aS2, const float* __restrict__ aS3,
    const float* __restrict__ aD0, const float* __restrict__ aD1,
    const float* __restrict__ aD2, const float* __restrict__ aD3,
    const u16* __restrict__ h0, const u16* __restrict__ h1,
    const u16* __restrict__ h2, const u16* __restrict__ h3,
    u32* __restrict__ o0, u32* __restrict__ o1,
    u32* __restrict__ o2, u32* __restrict__ o3,
    int N, int E)
{
  const int r = blockIdx.y;
  const float* aS = (r == 0) ? aS0 : (r == 1) ? aS1 : (r == 2) ? aS2 : aS3;
  const float* aD = (r == 0) ? aD0 : (r == 1) ? aD1 : (r == 2) ? aD2 : aD3;
  const u16*   h  = (r == 0) ? h0  : (r == 1) ? h1  : (r == 2) ? h2  : h3;
  u32*         o  = (r == 0) ? o0  : (r == 1) ? o1  : (r == 2) ? o2  : o3;

  const int wave = threadIdx.x >> 6, lane = threadIdx.x & 63;
  const int n = blockIdx.x * 4 + wave;
  if (n >= N) return;
  const int head = lane >> 3;
  const int hw = (lane >> 2) & 7;
  const int ew = lane & 3;
  const int srcb = head * 4;
  const int idx = r * N + n;
  const int p0 = off[idx];
  const int p1 = (idx + 1 < 4 * N) ? off[idx + 1] : 4 * E;
  const float aDw = aD[n * 8 + hw];
  const u32* h32 = (const u32*)h;

  float acc0 = 0.f, acc1 = 0.f, den = 0.f;
  int p = p0;
  for (; p + 4 <= p1; p += 4) {
    const int s0 = ssrc[p], s1 = ssrc[p + 1], s2 = ssrc[p + 2], s3 = ssrc[p + 3];
    const int sw = (ew & 1) ? ((ew & 2) ? s3 : s1) : ((ew & 2) ? s2 : s0);
    float lw = aS[sw * 8 + hw] + aDw;
    lw = fmaxf(lw, 0.2f * lw);
    const float wme = __expf(lw);
    const float w0 = __shfl(wme, srcb + 0);
    const float w1 = __shfl(wme, srcb + 1);
    const float w2 = __shfl(wme, srcb + 2);
    const float w3 = __shfl(wme, srcb + 3);
    const u32 v0 = h32[s0 * 64 + lane];
    const u32 v1 = h32[s1 * 64 + lane];
    const u32 v2 = h32[s2 * 64 + lane];
    const u32 v3 = h32[s3 * 64 + lane];
    den += (w0 + w1) + (w2 + w3);
    acc0 += w0 * blo(v0) + w1 * blo(v1) + w2 * blo(v2) + w3 * blo(v3);
    acc1 += w0 * bhi(v0) + w1 * bhi(v1) + w2 * bhi(v2) + w3 * bhi(v3);
  }
  const int rem = p1 - p;
  if (rem > 0) {
    const int s0 = ssrc[p];
    const int s1 = ssrc[(rem > 1) ? p + 1 : p];
    const int s2 = ssrc[(rem > 2) ? p + 2 : p];
    const int swi = (ew < rem) ? ew : 0;
    const int sw = (swi == 0) ? s0 : (swi == 1) ? s1 : s2;
    float lw = aS[sw * 8 + hw] + aDw;
    lw = fmaxf(lw, 0.2f * lw);
    const float wme = __expf(lw);
    const float w0 = __shfl(wme, srcb + 0);
    float w1 = __shfl(wme, srcb + 1);
    float w2 = __shfl(wme, srcb + 2);
    w1 = (rem > 1) ? w1 : 0.f;
    w2 = (rem > 2) ? w2 : 0.f;
    const u32 v0 = h32[s0 * 64 + lane];
    const u32 v1 = h32[s1 * 64 + lane];
    const u32 v2 = h32[s2 * 64 + lane];
    den += w0 + w1 + w2;
    acc0 += w0 * blo(v0) + w1 * blo(v1) + w2 * blo(v2);
    acc1 += w0 * bhi(v0) + w1 * bhi(v1) + w2 * bhi(v2);
  }
  const float inv = __fdividef(1.f, den + 1e-16f);
  const float r0 = fmaxf(acc0 * inv, 0.f);
  const float r1 = fmaxf(acc1 * inv, 0.f);
  o[n * 64 + lane] = (u32)f2bf(r0) | ((u32)f2bf(r1) << 16);
}

// ---------------------------------------------------------------------------
// K2: fused {bn 5-moment stats (attn-independent) | MFMA semantic score}.
// sem stages WkT into LDS via uint4; stats blocks reuse the LDS as scratch.
// ---------------------------------------------------------------------------
__global__ __launch_bounds__(256) void fused2_kernel(
    const u32* __restrict__ oba, const u32* __restrict__ oaa,
    const u32* __restrict__ oab, const u32* __restrict__ obb,
    const u16* __restrict__ WkT, const float* __restrict__ bk,
    const float* __restrict__ q, float* __restrict__ scores,
    float* __restrict__ sums_a, float* __restrict__ sums_b,
    int N, int R, int gproj)
{
  __shared__ __align__(16) u16 WTl[128 * 136];
  __shared__ float red[4];
  const int tid = threadIdx.x;
  const int bid = blockIdx.x;

  if (bid < 512) {                       // ---- bn 5-moment stats ----
    const int t = bid >> 8, bx = bid & 255;
    const u32* p0 = t ? oab : oba;
    const u32* p1 = t ? obb : oaa;
    float* sums = t ? sums_b : sums_a;
    const int tc = tid & 31, tr = tid >> 5;
    float s0[4] = {0,0,0,0}, s1[4] = {0,0,0,0};
    float q00[4] = {0,0,0,0}, q11[4] = {0,0,0,0}, q01[4] = {0,0,0,0};
    const int rend = min((bx + 1) * R, N);
    for (int row = bx * R + tr; row < rend; row += 8) {
      uint2 v0 = *(const uint2*)&p0[row * 64 + tc * 2];
      uint2 v1 = *(const uint2*)&p1[row * 64 + tc * 2];
      float r0[4] = {blo(v0.x), bhi(v0.x), blo(v0.y), bhi(v0.y)};
      float r1[4] = {blo(v1.x), bhi(v1.x), blo(v1.y), bhi(v1.y)};
#pragma unroll
      for (int j = 0; j < 4; ++j) {
        s0[j] += r0[j]; s1[j] += r1[j];
        q00[j] += r0[j] * r0[j]; q11[j] += r1[j] * r1[j];
        q01[j] += r0[j] * r1[j];
      }
    }
    float* sm = (float*)WTl;             // reuse LDS: 5 x 128 floats
    for (int i = tid; i < 640; i += 256) sm[i] = 0.f;
    __syncthreads();
#pragma unroll
    for (int j = 0; j < 4; ++j) {
      int f = tc * 4 + j;
      atomicAdd(&sm[f], s0[j]);
      atomicAdd(&sm[128 + f], s1[j]);
      atomicAdd(&sm[256 + f], q00[j]);
      atomicAdd(&sm[384 + f], q11[j]);
      atomicAdd(&sm[512 + f], q01[j]);
    }
    __syncthreads();
    for (int i = tid; i < 640; i += 256) atomicAdd(&sums[i], sm[i]);
    return;
  }

  // ---- sem_score ----
  const int sid = bid - 512;
  const int rel = sid & 3, bx = sid >> 2;
  const u32* op = (rel == 0) ? oba : (rel == 1) ? oaa : (rel == 2) ? oab : obb;
  const u16* o = (const u16*)op;

  // stage WkT -> LDS (aligned uint4, no conversion)
  const uint4* Wg = (const uint4*)WkT;
#pragma unroll
  for (int i = 0; i < 8; ++i) {
    int id = tid + 256 * i;
    uint4 v = Wg[id];
    int n = id >> 4, k8 = (id & 15) << 3;
    *(uint4*)&WTl[n * 136 + k8] = v;
  }
  __syncthreads();

  const int lane = tid & 63, wl = tid >> 6;
  const int col = lane & 15, g = lane >> 4;
  const int nb = bx * 64 + wl * 16;

  float bv[8], qv[8];
#pragma unroll
  for (int c = 0; c < 8; ++c) {
    bv[c] = bk[c * 16 + col];
    qv[c] = q[c * 16 + col];
  }

  const int arow = min(nb + col, N - 1);
  const u16* orow = o + (size_t)arow * 128;
  bf16x8 af[4];
#pragma unroll
  for (int t = 0; t < 4; ++t) af[t] = *(const bf16x8*)&orow[t * 32 + g * 8];

  f32x4 acc[8];
#pragma unroll
  for (int c = 0; c < 8; ++c) acc[c] = (f32x4){bv[c], bv[c], bv[c], bv[c]};

#pragma unroll
  for (int c = 0; c < 8; ++c) {
    const u16* wrow = &WTl[(c * 16 + col) * 136];
#pragma unroll
    for (int t = 0; t < 4; ++t) {
      bf16x8 bf = *(const bf16x8*)&wrow[t * 32 + g * 8];
      acc[c] = __builtin_amdgcn_mfma_f32_16x16x32_bf16(af[t], bf, acc[c], 0, 0, 0);
    }
  }

  float p = 0.f;
  const int rowbase = nb + g * 4;
#pragma unroll
  for (int c = 0; c < 8; ++c) {
#pragma unroll
    for (int i = 0; i < 4; ++i) {
      int node = rowbase + i;
      if (node < N) p += fast_tanh(acc[c][i]) * qv[c];
    }
  }
#pragma unroll
  for (int off = 32; off > 0; off >>= 1) p += __shfl_down(p, off);
  if (lane == 0) red[wl] = p;
  __syncthreads();
  if (tid == 0) atomicAdd(&scores[rel], red[0] + red[1] + red[2] + red[3]);
}

// ---------------------------------------------------------------------------
// bn_final: inline semantic softmax + moment combine + normalize + write.
// ---------------------------------------------------------------------------
__global__ __launch_bounds__(256) void bn_final_kernel(
    const u32* __restrict__ oba, const u32* __restrict__ oaa,
    const u32* __restrict__ oab, const u32* __restrict__ obb,
    const float* __restrict__ scores, const float* __restrict__ sums_a,
    const float* __restrict__ sums_b,
    const float* __restrict__ gamma, const float* __restrict__ beta,
    float* __restrict__ out, int N)
{
  const int t = blockIdx.y;
  const u32* o0 = t ? oab : oba;
  const u32* o1 = t ? obb : oaa;
  const float* sums = t ? sums_b : sums_a;
  float* op = out + (size_t)t * N * 128;

  const float invN = 1.f / (float)N;
  const float sc0 = scores[2 * t] * invN, sc1 = scores[2 * t + 1] * invN;
  const float m = fmaxf(sc0, sc1);
  const float e0 = expf(sc0 - m), e1 = expf(sc1 - m);
  const float einv = 1.f / (e0 + e1);
  const float a0 = e0 * einv, a1 = e1 * einv;

  __shared__ float scale[128], shift[128];
  if (threadIdx.x < 128) {
    int f = threadIdx.x;
    float S0 = sums[f], S1 = sums[128 + f];
    float Q00 = sums[256 + f], Q11 = sums[384 + f], Q01 = sums[512 + f];
    float mu = (a0 * S0 + a1 * S1) * invN;
    float msq = (a0 * a0 * Q00 + 2.f * a0 * a1 * Q01 + a1 * a1 * Q11) * invN;
    float var = fmaxf(msq - mu * mu, 0.f);
    float rs = rsqrtf(var + 1e-5f);
    float gm = gamma[f] * rs;
    scale[f] = gm;
    shift[f] = beta[f] - mu * gm;
  }
  __syncthreads();
  size_t total = (size_t)N * 128;
  for (size_t base = ((size_t)blockIdx.x * 256 + threadIdx.x) * 8; base < total;
       base += (size_t)gridDim.x * 2048) {
    int f0 = (int)(base & 127);
    uint4 p = *(const uint4*)&o0[base >> 1];
    uint4 q = *(const uint4*)&o1[base >> 1];
    float4 r0, r1;
    r0.x = (a0 * blo(p.x) + a1 * blo(q.x)) * scale[f0 + 0] + shift[f0 + 0];
    r0.y = (a0 * bhi(p.x) + a1 * bhi(q.x)) * scale[f0 + 1] + shift[f0 + 1];
    r0.z = (a0 * blo(p.y) + a1 * blo(q.y)) * scale[f0 + 2] + shift[f0 + 2];
    r0.w = (a0 * bhi(p.y) + a1 * bhi(q.y)) * scale[f0 + 3] + shift[f0 + 3];
    r1.x = (a0 * blo(p.z) + a1 * blo(q.z)) * scale[f0 + 4] + shift[f0 + 4];
    r1.y = (a0 * bhi(p.z) + a1 * bhi(q.z)) * scale[f0 + 5] + shift[f0 + 5];
    r1.z = (a0 * blo(p.w) + a1 * blo(q.w)) * scale[f0 + 6] + shift[f0 + 6];
    r1.w = (a0 * bhi(p.w) + a1 * bhi(q.w)) * scale[f0 + 7] + shift[f0 + 7];
    *(float4*)&op[base] = r0;
    *(float4*)&op[base + 4] = r1;
  }
}

extern "C" void kernel_launch(void* const* d_in, const int* in_sizes, int n_in,
                              void* d_out, int out_size, void* d_ws, size_t ws_size,
                              hipStream_t stream)
{
  const float* x_a      = (const float*)d_in[0];
  const float* x_b      = (const float*)d_in[1];
  const int* ei_ab      = (const int*)d_in[2];
  const int* ei_ba      = (const int*)d_in[3];
  const int* ei_aa      = (const int*)d_in[4];
  const int* ei_bb      = (const int*)d_in[5];
  const float* W_a      = (const float*)d_in[6];
  const float* b_a      = (const float*)d_in[7];
  const float* W_b      = (const float*)d_in[8];
  const float* b_b      = (const float*)d_in[9];
  const float* att_ab_s = (const float*)d_in[10];
  const float* att_ab_d = (const float*)d_in[11];
  const float* att_ba_s = (const float*)d_in[12];
  const float* att_ba_d = (const float*)d_in[13];
  const float* att_aa_s = (const float*)d_in[14];
  const float* att_aa_d = (const float*)d_in[15];
  const float* att_bb_s = (const float*)d_in[16];
  const float* att_bb_d = (const float*)d_in[17];
  const float* Wk       = (const float*)d_in[18];
  const float* bk       = (const float*)d_in[19];
  const float* q        = (const float*)d_in[20];
  const float* gamma    = (const float*)d_in[21];
  const float* beta     = (const float*)d_in[22];

  const int N = in_sizes[0] / 128;
  const int E = in_sizes[2] / 2;

  char* wp = (char*)d_ws;
  auto alloc = [&](size_t bytes) -> void* {
    void* p = (void*)wp;
    wp += (bytes + 255) & ~(size_t)255;
    return p;
  };
  u16* h_a = (u16*)alloc((size_t)N * 128 * 2);
  u16* h_b = (u16*)alloc((size_t)N * 128 * 2);
  float* A[8];
  for (int i = 0; i < 8; ++i) A[i] = (float*)alloc((size_t)N * 8 * 4);
  int* off    = (int*)alloc((size_t)4 * N * 4);
  int* cursor = (int*)alloc((size_t)4 * N * 4);
  int* bsum   = (int*)alloc(1024);
  int* ssrc   = (int*)alloc((size_t)4 * E * 4);
  u32* o_ab = (u32*)alloc((size_t)N * 64 * 4);   // packed relu bf16
  u32* o_ba = (u32*)alloc((size_t)N * 64 * 4);
  u32* o_aa = (u32*)alloc((size_t)N * 64 * 4);
  u32* o_bb = (u32*)alloc((size_t)N * 64 * 4);
  float* scores = (float*)alloc(16);             // 256B slot
  float* sums_a = (float*)alloc(2560);           // 5 x 128 f32
  float* sums_b = (float*)alloc(2560);
  u16* WT_a = (u16*)alloc(128 * 128 * 2);
  u16* WT_b = (u16*)alloc(128 * 128 * 2);
  u16* WT_k = (u16*)alloc(128 * 128 * 2);
  if ((size_t)(wp - (char*)d_ws) > ws_size) return;

  // --- prep: weight transpose-convert + zero off + zero scores/sums span ---
  const int M = 4 * N;
  const int Z = (M + 2047) / 2048;
  prep_kernel<<<192 + Z + 1, 256, 0, stream>>>(W_a, W_b, Wk, WT_a, WT_b, WT_k,
                                               off, M, scores, 1344);

  // --- K1: proj (both types) | hist (4 rel, 4 edges/thread) ---
  // relation order: 0=ab 1=ba 2=aa 3=bb
  // type a att slots: ab_s, aa_s, aa_d, ba_d -> A[0..3]
  // type b att slots: ab_d, bb_s, bb_d, ba_s -> A[4..7]
  const int gproj = (N + 63) / 64;
  const int gEh = (E + 1023) / 1024;
  const int nH = 4 * gEh;
  const int g1total = 2 * gproj + nH;
  fused1_kernel<<<g1total, 256, 0, stream>>>(
      x_a, x_b, WT_a, WT_b, b_a, b_b,
      att_ab_s, att_aa_s, att_aa_d, att_ba_d,
      att_ab_d, att_bb_s, att_bb_d, att_ba_s,
      h_a, h_b,
      A[0], A[1], A[2], A[3], A[4], A[5], A[6], A[7],
      ei_ab, ei_ba, ei_aa, ei_bb,
      off, N, E, gproj, nH);

  // --- CSR scans + scatter (scan2 folded into scan3) ---
  const int G1 = (M + 2047) / 2048;          // <= 256 for N <= 131072
  scan1_kernel<<<G1, 256, 0, stream>>>(off, M, bsum);
  scan3_kernel<<<G1, 256, 0, stream>>>(off, bsum, M, cursor);
  const int gE = (E + 255) / 256;
  dim3 gsc(gE, 4);
  scatter_kernel<<<gsc, 256, 0, stream>>>(ei_ab, ei_ba, ei_aa, ei_bb, E, N, cursor, ssrc);

  // --- fused softmax + aggregate ---
  dim3 gag((N + 3) / 4, 4);
  aggregate_kernel<<<gag, 256, 0, stream>>>(
      off, ssrc,
      A[0], A[7], A[1], A[5],          // aS per relation: ab,ba,aa,bb
      A[4], A[3], A[2], A[6],          // aD per relation
      h_a, h_b, h_a, h_b,
      o_ab, o_ba, o_aa, o_bb, N, E);

  // --- K2: bn 5-moment stats | semantic scores (slot order ba,aa,ab,bb) ---
  const int R = (N + 255) / 256;
  const int g2total = 512 + 4 * gproj;
  fused2_kernel<<<g2total, 256, 0, stream>>>(
      o_ba, o_aa, o_ab, o_bb, WT_k, bk, q, scores, sums_a, sums_b, N, R, gproj);

  // --- bn_final with inline softmax + moment combine ---
  float* out = (float*)d_out;
  dim3 gbf(1024, 2);
  bn_final_kernel<<<gbf, 256, 0, stream>>>(o_ba, o_aa, o_ab, o_bb, scores,
                                           sums_a, sums_b, gamma, beta, out, N);
}